// Round 12
// baseline (123.493 us; speedup 1.0000x reference)
//
#include <hip/hip_runtime.h>

#define BB 8
#define CC 64
#define HH 96
#define WW 96
#define OO 64
#define KK 3
#define K2 9
#define HW (HH*WW)      // 9216
#define NOFF 18
#define NPIX (BB*HW)    // 73728
#define MT 64           // pixels per dcn block
#define NTILE (HW/MT)   // 144 tiles per image
#define NXCD 8

typedef _Float16 f16;
typedef __attribute__((ext_vector_type(2))) _Float16 f16x2;
typedef __attribute__((ext_vector_type(4))) _Float16 f16x4;
typedef __attribute__((ext_vector_type(4))) float f32x4;
typedef __attribute__((ext_vector_type(2))) unsigned int uint2v;
typedef __attribute__((ext_vector_type(4))) unsigned int uint4v;

// Legacy CDNA spelling — no __has_builtin guard (false on host pass, R8 lesson)
#define MFMA16(a,b,c) __builtin_amdgcn_mfma_f32_16x16x16f16(a,b,c,0,0,0)

#if __has_builtin(__builtin_amdgcn_fdot2)
__device__ __forceinline__ float dot2u(unsigned a, unsigned b, float c) {
  return __builtin_amdgcn_fdot2(__builtin_bit_cast(f16x2, a),
                                __builtin_bit_cast(f16x2, b), c, false);
}
#else
__device__ __forceinline__ float dot2u(unsigned a, unsigned b, float c) {
  f16x2 ha = __builtin_bit_cast(f16x2, a), hb = __builtin_bit_cast(f16x2, b);
  return c + (float)ha[0] * (float)hb[0] + (float)ha[1] * (float)hb[1];
}
#endif

__device__ __forceinline__ f16x2 bch(unsigned u) { return __builtin_bit_cast(f16x2, u); }
__device__ __forceinline__ unsigned bcu(f16x2 h) { return __builtin_bit_cast(unsigned, h); }
__device__ __forceinline__ f16x4 fq(unsigned a, unsigned b) {
  uint2v u = {a, b};
  return __builtin_bit_cast(f16x4, u);
}

// XCD-aware block remap: 1152 blocks = 8 XCDs x 144 -> image j on XCD j
__device__ __forceinline__ int xcd_remap(int bid) {
  return (bid & 7) * (NPIX / 64 / NXCD) + (bid >> 3);
}

// ---------------- Kernel T: NCHW fp32 -> NHWC f16 (verified R5 + swizzle) ---
__global__ __launch_bounds__(256) void transpose_kernel(
    const float* __restrict__ x, unsigned short* __restrict__ xt) {
  int t = threadIdx.x;
  int px = xcd_remap(blockIdx.x) * 64 + (t & 63);
  int cg = t >> 6;
  int b = px / HW, hw = px % HW;
  const float* xp = x + (size_t)b * CC * HW + (size_t)(cg * 16) * HW + hw;
  f16 r[16];
  #pragma unroll
  for (int i = 0; i < 16; ++i) r[i] = (f16)xp[i * HW];
  uint4v v0, v1;
  #pragma unroll
  for (int q = 0; q < 4; ++q) {
    f16x2 a = {r[q*2], r[q*2+1]};       v0[q] = bcu(a);
    f16x2 bq = {r[8+q*2], r[8+q*2+1]};  v1[q] = bcu(bq);
  }
  uint4v* dst = (uint4v*)(xt + (size_t)px * CC + cg * 16);
  dst[0] = v0; dst[1] = v1;
}

// ---------------- Kernel W: w_dcn [O][C][K2] fp32 -> wt [K2][O][C] f16 ------
__global__ void wprep_kernel(const float* __restrict__ w_dcn,
                             unsigned short* __restrict__ wt) {
  int idx = blockIdx.x * 256 + threadIdx.x;
  int k = idx / (OO * CC);
  int o = (idx / CC) % OO;
  int c = idx % CC;
  f16 h = (f16)w_dcn[(o * CC + c) * K2 + k];
  wt[idx] = __builtin_bit_cast(unsigned short, h);
}

// ---------------- Kernel O: offset conv via dot2 (verified R5 + swizzle) ----
#define JW 72
#define DOT4(xv, wv, a) do { a = dot2u((xv)[0],(wv)[0],a); a = dot2u((xv)[1],(wv)[1],a); \
                             a = dot2u((xv)[2],(wv)[2],a); a = dot2u((xv)[3],(wv)[3],a); } while(0)
#define DECLSET(R) uint4v R##0,R##1,R##2,R##3,R##4,R##5,R##6,R##7; bool vld##R = false;
#define LOADT(kt_, R) do { int ky=(kt_)/3, kx=(kt_)%3; int y=h-1+ky, xx=w-1+kx; \
  vld##R = ((unsigned)y<HH)&&((unsigned)xx<WW); \
  int yc=min(max(y,0),HH-1), xc=min(max(xx,0),WW-1); \
  const uint4v* xr_ = xtb + (size_t)(yc*WW+xc)*8; \
  R##0=xr_[0];R##1=xr_[1];R##2=xr_[2];R##3=xr_[3];R##4=xr_[4];R##5=xr_[5];R##6=xr_[6];R##7=xr_[7]; } while(0)
#define USET(kt_, R) do { if (vld##R) { \
  _Pragma("unroll") \
  for (int ji = 0; ji < 5; ++ji) { int j = jg + ji*4; \
    const uint4v* wr_ = (const uint4v*)&wl[((kt_)*NOFF + j)*JW]; \
    float a = acc[ji]; \
    DOT4(R##0,wr_[0],a); DOT4(R##1,wr_[1],a); DOT4(R##2,wr_[2],a); DOT4(R##3,wr_[3],a); \
    DOT4(R##4,wr_[4],a); DOT4(R##5,wr_[5],a); DOT4(R##6,wr_[6],a); DOT4(R##7,wr_[7],a); \
    if (j < NOFF) acc[ji] = a; } } } while(0)

__global__ __launch_bounds__(256) void offconv_kernel(
    const unsigned short* __restrict__ xt, const float* __restrict__ w_off,
    const float* __restrict__ b_off, float* __restrict__ offset) {
  __shared__ unsigned short wl[K2 * NOFF * JW + 2 * JW];
  int t = threadIdx.x;
  for (int i = t; i < K2 * NOFF * CC; i += 256) {
    int kt = i / (NOFF * CC);
    int r = i - kt * (NOFF * CC);
    int j = r >> 6, c = r & 63;
    f16 h = (f16)w_off[(j * CC + c) * K2 + kt];
    wl[(kt * NOFF + j) * JW + c] = __builtin_bit_cast(unsigned short, h);
  }
  __syncthreads();

  int px = xcd_remap(blockIdx.x) * 64 + (t >> 2);
  int jg = t & 3;
  int b = px / HW, hw = px % HW;
  int h = hw / WW, w = hw % WW;

  float acc[5];
  #pragma unroll
  for (int ji = 0; ji < 5; ++ji) {
    int j = jg + ji * 4;
    acc[ji] = (j < NOFF) ? b_off[j] : 0.f;
  }

  const uint4v* xtb = (const uint4v*)(xt + (size_t)b * HW * CC);
  DECLSET(A); DECLSET(B);
  LOADT(0, A);
  LOADT(1, B);
  #pragma unroll
  for (int kt = 0; kt < 7; kt += 2) {
    USET(kt, A);     LOADT(kt + 2, A);
    USET(kt + 1, B); if (kt + 3 < K2) LOADT(kt + 3, B);
  }
  USET(8, A);

  float* op = offset + (size_t)b * NOFF * HW + hw;
  #pragma unroll
  for (int ji = 0; ji < 5; ++ji) {
    int j = jg + ji * 4;
    if (j < NOFF) op[j * HW] = acc[ji];
  }
}

// ---------------- Kernel D: dcn MFMA 16x16x16, all-register, barrier-free ---
// k<->channel map per chunk q: kappa(q, lh, e) = 16*lh + 4*q + e (bijective
// per chunk; SAME map for A and B -> contraction exact). With this map each
// lane's 16 channels are the CONTIGUOUS 32 B [32*lh .. +31] of its pixel row:
//   A: gather 4 corners x 2 x 16 B, blend in-register (same pk math as R5..R11)
//   B: 2 x 16 B per nb straight from wt (same bytes for every block -> L2-hot)
// No ds_write / ds_read / barrier in the main loop; waves free-run.
// MFMA16 layout (HW-verified R9): A row = l&15, k = 4*(l>>4)+e;
// B n = l&15; D col = l&15, row = (l>>4)*4 + reg.
__global__ __launch_bounds__(256) void dcn_mfma16(
    const unsigned short* __restrict__ xt,   // [B][HW][C] f16
    const float* __restrict__ offset,        // [B][18][HW] fp32
    const unsigned short* __restrict__ wt,   // [K2][O][C] f16
    float* __restrict__ out) {
  __shared__ uint4v prm[576];   // {i01, i23, w01(f16x2), w23(f16x2)} per (k,m)

  int t = threadIdx.x;
  int blk = xcd_remap(blockIdx.x);
  int b = blk / NTILE;
  int hw0 = (blk % NTILE) * MT;

  const char*  xb   = (const char*)(xt + (size_t)b * HW * CC);
  const float* offb = offset + (size_t)b * NOFF * HW + hw0;

  // ---- phase 0: bilinear params, packed 16 B/entry (math verified R3..R11) -
  for (int p = t; p < 576; p += 256) {
    int k = p >> 6, m = p & 63;
    int hw = hw0 + m;
    int h = hw / WW, w = hw % WW;
    int ky = k / KK, kx = k % KK;
    float py = offb[(2 * k) * HW + m]     + (float)(h - 1 + ky);
    float px = offb[(2 * k + 1) * HW + m] + (float)(w - 1 + kx);
    float y0f = floorf(py), x0f = floorf(px);
    float wy = py - y0f, wx = px - x0f;
    int y0 = (int)y0f, x0 = (int)x0f;
    int y1 = y0 + 1, x1 = x0 + 1;
    bool vy0 = (unsigned)y0 < HH, vy1 = (unsigned)y1 < HH;
    bool vx0 = (unsigned)x0 < WW, vx1 = (unsigned)x1 < WW;
    int cy0 = min(max(y0, 0), HH - 1), cy1 = min(max(y1, 0), HH - 1);
    int cx0 = min(max(x0, 0), WW - 1), cx1 = min(max(x1, 0), WW - 1);
    float g00 = (1.f - wy) * (1.f - wx) * ((vy0 && vx0) ? 1.f : 0.f);
    float g01 = (1.f - wy) * wx         * ((vy0 && vx1) ? 1.f : 0.f);
    float g10 = wy * (1.f - wx)         * ((vy1 && vx0) ? 1.f : 0.f);
    float g11 = wy * wx                 * ((vy1 && vx1) ? 1.f : 0.f);
    unsigned i01 = (unsigned)(cy0 * WW + cx0) | ((unsigned)(cy0 * WW + cx1) << 16);
    unsigned i23 = (unsigned)(cy1 * WW + cx0) | ((unsigned)(cy1 * WW + cx1) << 16);
    f16x2 wa = {(f16)g00, (f16)g01};
    f16x2 wb = {(f16)g10, (f16)g11};
    prm[p] = (uint4v){i01, i23, bcu(wa), bcu(wb)};
  }
  __syncthreads();   // the ONLY block-wide barrier

  // wave geometry (verified R9)
  int wv = t >> 6;
  int l  = t & 63;
  int lr = l & 15, lh = l >> 4;
  int Ra = wv * 16 + lr;          // this lane's pixel row in the 64-pixel tile
  int cB = lh * 32;               // this lane's 32-B channel segment

  f32x4 acc[4];
  #pragma unroll
  for (int nb = 0; nb < 4; ++nb) acc[nb] = (f32x4){0.f, 0.f, 0.f, 0.f};

  #pragma unroll
  for (int k = 0; k < K2; ++k) {
    // ---- per-lane params for its own pixel ----
    uint4v e = prm[k * 64 + Ra];
    int i0 = (int)(e[0] & 0xffffu) << 7;
    int i1 = (int)(e[0] >> 16) << 7;
    int i2 = (int)(e[1] & 0xffffu) << 7;
    int i3 = (int)(e[1] >> 16) << 7;

    // ---- A: gather 4 corners x 32 B, blend (same pk math as R5..R11) ----
    uint4v c0a = *(const uint4v*)(xb + i0 + cB);
    uint4v c0b = *(const uint4v*)(xb + i0 + cB + 16);
    uint4v c1a = *(const uint4v*)(xb + i1 + cB);
    uint4v c1b = *(const uint4v*)(xb + i1 + cB + 16);
    uint4v c2a = *(const uint4v*)(xb + i2 + cB);
    uint4v c2b = *(const uint4v*)(xb + i2 + cB + 16);
    uint4v c3a = *(const uint4v*)(xb + i3 + cB);
    uint4v c3b = *(const uint4v*)(xb + i3 + cB + 16);
    f16x2 wA = bch(e[2]), wB = bch(e[3]);
    f16x2 p0 = {wA[0], wA[0]}, p1 = {wA[1], wA[1]};
    f16x2 p2 = {wB[0], wB[0]}, p3 = {wB[1], wB[1]};
    uint4v pa, pb2;
    #pragma unroll
    for (int q = 0; q < 4; ++q) {
      f16x2 s  = p0 * bch(c0a[q]) + p1 * bch(c1a[q])
               + p2 * bch(c2a[q]) + p3 * bch(c3a[q]);
      pa[q] = bcu(s);
      f16x2 s2 = p0 * bch(c0b[q]) + p1 * bch(c1b[q])
               + p2 * bch(c2b[q]) + p3 * bch(c3b[q]);
      pb2[q] = bcu(s2);
    }
    f16x4 a0 = fq(pa[0],  pa[1]);    // channels 16*lh + 0..3
    f16x4 a1 = fq(pa[2],  pa[3]);    // channels 16*lh + 4..7
    f16x4 a2 = fq(pb2[0], pb2[1]);   // channels 16*lh + 8..11
    f16x4 a3 = fq(pb2[2], pb2[3]);   // channels 16*lh + 12..15

    // ---- B: this lane's 32 B of each o-row (L2-hot, coalesced) ----
    const char* wrow = (const char*)wt + (size_t)k * OO * (CC * 2);
    #pragma unroll
    for (int nb = 0; nb < 4; ++nb) {
      const char* wp = wrow + (size_t)(nb * 16 + lr) * (CC * 2) + cB;
      uint4v wv0 = *(const uint4v*)wp;
      uint4v wv1 = *(const uint4v*)(wp + 16);
      f16x4 b0 = fq(wv0[0], wv0[1]);
      f16x4 b1 = fq(wv0[2], wv0[3]);
      f16x4 b2 = fq(wv1[0], wv1[1]);
      f16x4 b3 = fq(wv1[2], wv1[3]);
      acc[nb] = MFMA16(a0, b0, acc[nb]);
      acc[nb] = MFMA16(a1, b1, acc[nb]);
      acc[nb] = MFMA16(a2, b2, acc[nb]);
      acc[nb] = MFMA16(a3, b3, acc[nb]);
    }
  }

  // ---- epilogue (verified R9) ----
  float* ob = out + (size_t)b * OO * HW;
  #pragma unroll
  for (int nb = 0; nb < 4; ++nb) {
    int o = nb * 16 + lr;
    int m = wv * 16 + lh * 4;
    *(f32x4*)(ob + (size_t)o * HW + hw0 + m) = acc[nb];
  }
}

extern "C" void kernel_launch(void* const* d_in, const int* in_sizes, int n_in,
                              void* d_out, int out_size, void* d_ws, size_t ws_size,
                              hipStream_t stream) {
  const float* x     = (const float*)d_in[0];
  const float* w_off = (const float*)d_in[1];
  const float* b_off = (const float*)d_in[2];
  const float* w_dcn = (const float*)d_in[3];
  float* out = (float*)d_out;

  char* ws = (char*)d_ws;
  float* offset = (float*)ws;                                      // 5,308,416 B
  unsigned short* xtp = (unsigned short*)(ws + 5308416);           // 9,437,184 B
  unsigned short* wtp = (unsigned short*)(ws + 5308416 + 9437184); //    73,728 B

  transpose_kernel<<<NPIX / 64, 256, 0, stream>>>(x, xtp);
  wprep_kernel<<<(K2 * OO * CC) / 256, 256, 0, stream>>>(w_dcn, wtp);
  offconv_kernel<<<NPIX / 64, 256, 0, stream>>>(xtp, w_off, b_off, offset);
  dcn_mfma16<<<NPIX / 64, 256, 0, stream>>>(xtp, offset, wtp, out);
}

// Round 14
// 102.950 us; speedup vs baseline: 1.1995x; 1.1995x over previous
//
#include <hip/hip_runtime.h>

#define BB 8
#define CC 64
#define HH 96
#define WW 96
#define OO 64
#define KK 3
#define K2 9
#define HW (HH*WW)      // 9216
#define NOFF 18
#define NPIX (BB*HW)    // 73728
#define MT 32           // pixels per dcn block (96 = 3*32: tiles never cross rows)
#define NTILE (HW/MT)   // 288 tiles per image
#define NXCD 8
// dcn LDS window: 5 rows x 36 cols of 128-B pixel rows, padded stride 144 B
#define WR 5
#define WC 36
#define WROWB 144
#define NWIN (WR*WC)    // 180

typedef _Float16 f16;
typedef __attribute__((ext_vector_type(2))) _Float16 f16x2;
typedef __attribute__((ext_vector_type(4))) _Float16 f16x4;
typedef __attribute__((ext_vector_type(4))) float f32x4;
typedef __attribute__((ext_vector_type(2))) unsigned int uint2v;
typedef __attribute__((ext_vector_type(4))) unsigned int uint4v;

// Legacy CDNA spelling — no __has_builtin guard (false on host pass, R8 lesson)
#define MFMA16(a,b,c) __builtin_amdgcn_mfma_f32_16x16x16f16(a,b,c,0,0,0)

#if __has_builtin(__builtin_amdgcn_fdot2)
__device__ __forceinline__ float dot2u(unsigned a, unsigned b, float c) {
  return __builtin_amdgcn_fdot2(__builtin_bit_cast(f16x2, a),
                                __builtin_bit_cast(f16x2, b), c, false);
}
#else
__device__ __forceinline__ float dot2u(unsigned a, unsigned b, float c) {
  f16x2 ha = __builtin_bit_cast(f16x2, a), hb = __builtin_bit_cast(f16x2, b);
  return c + (float)ha[0] * (float)hb[0] + (float)ha[1] * (float)hb[1];
}
#endif

__device__ __forceinline__ f16x2 bch(unsigned u) { return __builtin_bit_cast(f16x2, u); }
__device__ __forceinline__ unsigned bcu(f16x2 h) { return __builtin_bit_cast(unsigned, h); }
__device__ __forceinline__ f16x4 fq(unsigned a, unsigned b) {
  uint2v u = {a, b};
  return __builtin_bit_cast(f16x4, u);
}

// XCD-aware bijective remap (grid % 8 == 0)
__device__ __forceinline__ int xcd_remap(int bid, int per) {
  return (bid & 7) * per + (bid >> 3);
}

// ---------------- Kernel T: NCHW fp32 -> NHWC f16 (verified R5 + swizzle) ---
__global__ __launch_bounds__(256) void transpose_kernel(
    const float* __restrict__ x, unsigned short* __restrict__ xt) {
  int t = threadIdx.x;
  int px = xcd_remap(blockIdx.x, NPIX / 64 / NXCD) * 64 + (t & 63);
  int cg = t >> 6;
  int b = px / HW, hw = px % HW;
  const float* xp = x + (size_t)b * CC * HW + (size_t)(cg * 16) * HW + hw;
  f16 r[16];
  #pragma unroll
  for (int i = 0; i < 16; ++i) r[i] = (f16)xp[i * HW];
  uint4v v0, v1;
  #pragma unroll
  for (int q = 0; q < 4; ++q) {
    f16x2 a = {r[q*2], r[q*2+1]};       v0[q] = bcu(a);
    f16x2 bq = {r[8+q*2], r[8+q*2+1]};  v1[q] = bcu(bq);
  }
  uint4v* dst = (uint4v*)(xt + (size_t)px * CC + cg * 16);
  dst[0] = v0; dst[1] = v1;
}

// ---------------- Kernel W: w_dcn [O][C][K2] fp32 -> wt [K2][O][C] f16 ------
__global__ void wprep_kernel(const float* __restrict__ w_dcn,
                             unsigned short* __restrict__ wt) {
  int idx = blockIdx.x * 256 + threadIdx.x;
  int k = idx / (OO * CC);
  int o = (idx / CC) % OO;
  int c = idx % CC;
  f16 h = (f16)w_dcn[(o * CC + c) * K2 + k];
  wt[idx] = __builtin_bit_cast(unsigned short, h);
}

// ---------------- Kernel O: offset conv via dot2 (verified R5 + swizzle) ----
#define JW 72
#define DOT4(xv, wv, a) do { a = dot2u((xv)[0],(wv)[0],a); a = dot2u((xv)[1],(wv)[1],a); \
                             a = dot2u((xv)[2],(wv)[2],a); a = dot2u((xv)[3],(wv)[3],a); } while(0)
#define DECLSET(R) uint4v R##0,R##1,R##2,R##3,R##4,R##5,R##6,R##7; bool vld##R = false;
#define LOADT(kt_, R) do { int ky=(kt_)/3, kx=(kt_)%3; int y=h-1+ky, xx=w-1+kx; \
  vld##R = ((unsigned)y<HH)&&((unsigned)xx<WW); \
  int yc=min(max(y,0),HH-1), xc=min(max(xx,0),WW-1); \
  const uint4v* xr_ = xtb + (size_t)(yc*WW+xc)*8; \
  R##0=xr_[0];R##1=xr_[1];R##2=xr_[2];R##3=xr_[3];R##4=xr_[4];R##5=xr_[5];R##6=xr_[6];R##7=xr_[7]; } while(0)
#define USET(kt_, R) do { if (vld##R) { \
  _Pragma("unroll") \
  for (int ji = 0; ji < 5; ++ji) { int j = jg + ji*4; \
    const uint4v* wr_ = (const uint4v*)&wl[((kt_)*NOFF + j)*JW]; \
    float a = acc[ji]; \
    DOT4(R##0,wr_[0],a); DOT4(R##1,wr_[1],a); DOT4(R##2,wr_[2],a); DOT4(R##3,wr_[3],a); \
    DOT4(R##4,wr_[4],a); DOT4(R##5,wr_[5],a); DOT4(R##6,wr_[6],a); DOT4(R##7,wr_[7],a); \
    if (j < NOFF) acc[ji] = a; } } } while(0)

__global__ __launch_bounds__(256) void offconv_kernel(
    const unsigned short* __restrict__ xt, const float* __restrict__ w_off,
    const float* __restrict__ b_off, float* __restrict__ offset) {
  __shared__ unsigned short wl[K2 * NOFF * JW + 2 * JW];
  int t = threadIdx.x;
  for (int i = t; i < K2 * NOFF * CC; i += 256) {
    int kt = i / (NOFF * CC);
    int r = i - kt * (NOFF * CC);
    int j = r >> 6, c = r & 63;
    f16 h = (f16)w_off[(j * CC + c) * K2 + kt];
    wl[(kt * NOFF + j) * JW + c] = __builtin_bit_cast(unsigned short, h);
  }
  __syncthreads();

  int px = xcd_remap(blockIdx.x, NPIX / 64 / NXCD) * 64 + (t >> 2);
  int jg = t & 3;
  int b = px / HW, hw = px % HW;
  int h = hw / WW, w = hw % WW;

  float acc[5];
  #pragma unroll
  for (int ji = 0; ji < 5; ++ji) {
    int j = jg + ji * 4;
    acc[ji] = (j < NOFF) ? b_off[j] : 0.f;
  }

  const uint4v* xtb = (const uint4v*)(xt + (size_t)b * HW * CC);
  DECLSET(A); DECLSET(B);
  LOADT(0, A);
  LOADT(1, B);
  #pragma unroll
  for (int kt = 0; kt < 7; kt += 2) {
    USET(kt, A);     LOADT(kt + 2, A);
    USET(kt + 1, B); if (kt + 3 < K2) LOADT(kt + 3, B);
  }
  USET(8, A);

  float* op = offset + (size_t)b * NOFF * HW + hw;
  #pragma unroll
  for (int ji = 0; ji < 5; ++ji) {
    int j = jg + ji * 4;
    if (j < NOFF) op[j * HW] = acc[ji];
  }
}

// ---------------- Kernel D: dcn MFMA, LDS-window gather + escape path -------
// R13 structure, fixed: window covers |offset|<1 but data max |offset|~1.24
// (sigma 0.24, max-order-statistic over 6.6e5 samples) -> R13's clamp was
// wrong for ~20 samples. Phase 0 now tests the UNCLAMPED window coords; if
// any corner falls outside, it stores image lin-indices + flag (bit 31) and
// the main loop takes R12's verified global-gather path for that lane.
// Window entry (ry,rx) holds image pixel (clamp(h0-2+ry), clamp(w0-2+rx));
// for in-window, image-clamped coords map exactly. Blend/MFMA math is
// bit-identical to R12 (absmax 0.015625).
__global__ __launch_bounds__(128) void dcn_mfma16(
    const unsigned short* __restrict__ xt,   // [B][HW][C] f16
    const float* __restrict__ offset,        // [B][18][HW] fp32
    const unsigned short* __restrict__ wt,   // [K2][O][C] f16
    float* __restrict__ out) {
  __shared__ char xwin[NWIN * WROWB];          // 25920 B
  __shared__ uint4v prm[K2 * MT];              // 288 x 16 B

  int t = threadIdx.x;
  int blk = xcd_remap(blockIdx.x, NPIX / MT / NXCD);
  int b = blk / NTILE;
  int hw0 = (blk % NTILE) * MT;
  int h0 = hw0 / WW, w0 = hw0 % WW;            // tile = row h0, cols w0..w0+31

  const char*  xb   = (const char*)(xt + (size_t)b * HW * CC);
  const float* offb = offset + (size_t)b * NOFF * HW + hw0;

  // ---- stage window: 180 rows x 128 B, coalesced, once ----
  for (int i = t; i < NWIN * 8; i += 128) {
    int row = i >> 3, seg = i & 7;
    int wr = row / WC, wc = row - wr * WC;
    int gy = min(max(h0 - 2 + wr, 0), HH - 1);
    int gx = min(max(w0 - 2 + wc, 0), WW - 1);
    *(uint4v*)&xwin[row * WROWB + (seg << 4)] =
        *(const uint4v*)(xb + (size_t)((gy * WW + gx) << 7) + (seg << 4));
  }

  // ---- phase 0: bilinear params (math verified R3..R12) ----
  for (int p = t; p < K2 * MT; p += 128) {
    int k = p >> 5, m = p & 31;
    int h = h0, w = w0 + m;
    int ky = k / KK, kx = k % KK;
    float py = offb[(2 * k) * HW + m]     + (float)(h - 1 + ky);
    float px = offb[(2 * k + 1) * HW + m] + (float)(w - 1 + kx);
    float y0f = floorf(py), x0f = floorf(px);
    float wy = py - y0f, wx = px - x0f;
    int y0 = (int)y0f, x0 = (int)x0f;
    int y1 = y0 + 1, x1 = x0 + 1;
    bool vy0 = (unsigned)y0 < HH, vy1 = (unsigned)y1 < HH;
    bool vx0 = (unsigned)x0 < WW, vx1 = (unsigned)x1 < WW;
    int cy0 = min(max(y0, 0), HH - 1), cy1 = min(max(y1, 0), HH - 1);
    int cx0 = min(max(x0, 0), WW - 1), cx1 = min(max(x1, 0), WW - 1);
    float g00 = (1.f - wy) * (1.f - wx) * ((vy0 && vx0) ? 1.f : 0.f);
    float g01 = (1.f - wy) * wx         * ((vy0 && vx1) ? 1.f : 0.f);
    float g10 = wy * (1.f - wx)         * ((vy1 && vx0) ? 1.f : 0.f);
    float g11 = wy * wx                 * ((vy1 && vx1) ? 1.f : 0.f);
    // unclamped window coords; escape if ANY corner outside the window
    int ry0 = cy0 - (h0 - 2), ry1 = cy1 - (h0 - 2);
    int rx0 = cx0 - (w0 - 2), rx1 = cx1 - (w0 - 2);
    bool inw = ((unsigned)ry0 < WR) && ((unsigned)ry1 < WR) &&
               ((unsigned)rx0 < WC) && ((unsigned)rx1 < WC);
    unsigned f0, f1;
    if (inw) {
      f0 = (unsigned)((ry0 * WC + rx0) * WROWB)
         | ((unsigned)((ry0 * WC + rx1) * WROWB) << 16);   // <=25776, bit15 clear
      f1 = (unsigned)((ry1 * WC + rx0) * WROWB)
         | ((unsigned)((ry1 * WC + rx1) * WROWB) << 16);
    } else {
      f0 = (unsigned)(cy0 * WW + cx0)
         | ((unsigned)(cy0 * WW + cx1) << 16) | 0x80000000u; // lin idx <=9215
      f1 = (unsigned)(cy1 * WW + cx0)
         | ((unsigned)(cy1 * WW + cx1) << 16);
    }
    f16x2 wa = {(f16)g00, (f16)g01};
    f16x2 wb = {(f16)g10, (f16)g11};
    prm[p] = (uint4v){f0, f1, bcu(wa), bcu(wb)};
  }
  __syncthreads();   // the ONLY block-wide barrier

  // wave geometry (verified R9/R12)
  int wv = t >> 6;                 // 0..1
  int l  = t & 63;
  int lr = l & 15, lh = l >> 4;
  int Ra = wv * 16 + lr;           // this lane's pixel (0..31)
  int cB = lh * 32;                // this lane's 32-B channel segment

  f32x4 acc[4];
  #pragma unroll
  for (int nb = 0; nb < 4; ++nb) acc[nb] = (f32x4){0.f, 0.f, 0.f, 0.f};

  #pragma unroll
  for (int k = 0; k < K2; ++k) {
    uint4v e = prm[k * MT + Ra];
    uint4v c0a, c0b, c1a, c1b, c2a, c2b, c3a, c3b;
    if ((int)e[0] >= 0) {
      // ---- common: gather 4 corners x 32 B from the LDS window ----
      int i0 = (int)(e[0] & 0xffffu);
      int i1 = (int)(e[0] >> 16);
      int i2 = (int)(e[1] & 0xffffu);
      int i3 = (int)(e[1] >> 16);
      c0a = *(const uint4v*)&xwin[i0 + cB];
      c0b = *(const uint4v*)&xwin[i0 + cB + 16];
      c1a = *(const uint4v*)&xwin[i1 + cB];
      c1b = *(const uint4v*)&xwin[i1 + cB + 16];
      c2a = *(const uint4v*)&xwin[i2 + cB];
      c2b = *(const uint4v*)&xwin[i2 + cB + 16];
      c3a = *(const uint4v*)&xwin[i3 + cB];
      c3b = *(const uint4v*)&xwin[i3 + cB + 16];
    } else {
      // ---- rare escape (~20 lanes grid-wide): R12 global gather ----
      int i0 = (int)(e[0] & 0x7fffu) << 7;
      int i1 = (int)((e[0] >> 16) & 0x7fffu) << 7;
      int i2 = (int)(e[1] & 0x7fffu) << 7;
      int i3 = (int)((e[1] >> 16) & 0x7fffu) << 7;
      c0a = *(const uint4v*)(xb + i0 + cB);
      c0b = *(const uint4v*)(xb + i0 + cB + 16);
      c1a = *(const uint4v*)(xb + i1 + cB);
      c1b = *(const uint4v*)(xb + i1 + cB + 16);
      c2a = *(const uint4v*)(xb + i2 + cB);
      c2b = *(const uint4v*)(xb + i2 + cB + 16);
      c3a = *(const uint4v*)(xb + i3 + cB);
      c3b = *(const uint4v*)(xb + i3 + cB + 16);
    }

    // ---- blend (bit-identical R12 math) ----
    f16x2 wA = bch(e[2]), wB = bch(e[3]);
    f16x2 p0 = {wA[0], wA[0]}, p1 = {wA[1], wA[1]};
    f16x2 p2 = {wB[0], wB[0]}, p3 = {wB[1], wB[1]};
    uint4v pa, pb2;
    #pragma unroll
    for (int q = 0; q < 4; ++q) {
      f16x2 s  = p0 * bch(c0a[q]) + p1 * bch(c1a[q])
               + p2 * bch(c2a[q]) + p3 * bch(c3a[q]);
      pa[q] = bcu(s);
      f16x2 s2 = p0 * bch(c0b[q]) + p1 * bch(c1b[q])
               + p2 * bch(c2b[q]) + p3 * bch(c3b[q]);
      pb2[q] = bcu(s2);
    }
    f16x4 a0 = fq(pa[0],  pa[1]);
    f16x4 a1 = fq(pa[2],  pa[3]);
    f16x4 a2 = fq(pb2[0], pb2[1]);
    f16x4 a3 = fq(pb2[2], pb2[3]);

    // ---- B: this lane's 32 B of each o-row straight from wt (L2-hot) ----
    const char* wrow = (const char*)wt + (size_t)k * OO * (CC * 2);
    #pragma unroll
    for (int nb = 0; nb < 4; ++nb) {
      const char* wp = wrow + (size_t)(nb * 16 + lr) * (CC * 2) + cB;
      uint4v wv0 = *(const uint4v*)wp;
      uint4v wv1 = *(const uint4v*)(wp + 16);
      f16x4 b0 = fq(wv0[0], wv0[1]);
      f16x4 b1 = fq(wv0[2], wv0[3]);
      f16x4 b2 = fq(wv1[0], wv1[1]);
      f16x4 b3 = fq(wv1[2], wv1[3]);
      acc[nb] = MFMA16(a0, b0, acc[nb]);
      acc[nb] = MFMA16(a1, b1, acc[nb]);
      acc[nb] = MFMA16(a2, b2, acc[nb]);
      acc[nb] = MFMA16(a3, b3, acc[nb]);
    }
  }

  // ---- epilogue (verified R9/R12) ----
  float* ob = out + (size_t)b * OO * HW;
  #pragma unroll
  for (int nb = 0; nb < 4; ++nb) {
    int o = nb * 16 + lr;
    int m = wv * 16 + lh * 4;
    *(f32x4*)(ob + (size_t)o * HW + hw0 + m) = acc[nb];
  }
}

extern "C" void kernel_launch(void* const* d_in, const int* in_sizes, int n_in,
                              void* d_out, int out_size, void* d_ws, size_t ws_size,
                              hipStream_t stream) {
  const float* x     = (const float*)d_in[0];
  const float* w_off = (const float*)d_in[1];
  const float* b_off = (const float*)d_in[2];
  const float* w_dcn = (const float*)d_in[3];
  float* out = (float*)d_out;

  char* ws = (char*)d_ws;
  float* offset = (float*)ws;                                      // 5,308,416 B
  unsigned short* xtp = (unsigned short*)(ws + 5308416);           // 9,437,184 B
  unsigned short* wtp = (unsigned short*)(ws + 5308416 + 9437184); //    73,728 B

  transpose_kernel<<<NPIX / 64, 256, 0, stream>>>(x, xtp);
  wprep_kernel<<<(K2 * OO * CC) / 256, 256, 0, stream>>>(w_dcn, wtp);
  offconv_kernel<<<NPIX / 64, 256, 0, stream>>>(xtp, w_off, b_off, offset);
  dcn_mfma16<<<NPIX / MT, 128, 0, stream>>>(xtp, offset, wtp, out);
}

// Round 15
// 94.269 us; speedup vs baseline: 1.3100x; 1.0921x over previous
//
#include <hip/hip_runtime.h>

#define BB 8
#define CC 64
#define HH 96
#define WW 96
#define OO 64
#define KK 3
#define K2 9
#define HW (HH*WW)      // 9216
#define NOFF 18
#define NPIX (BB*HW)    // 73728
#define MT 64           // pixels per dcn block: 2 rows x 32 cols
#define NTILE (HW/MT)   // 144 tiles per image (48 tile-rows x 3 tile-cols)
#define NXCD 8
// dcn LDS window: 6 rows x 36 cols of 128-B pixel rows, padded stride 144 B
#define WR 6
#define WC 36
#define WROWB 144
#define NWIN (WR*WC)    // 216

typedef _Float16 f16;
typedef __attribute__((ext_vector_type(2))) _Float16 f16x2;
typedef __attribute__((ext_vector_type(4))) _Float16 f16x4;
typedef __attribute__((ext_vector_type(4))) float f32x4;
typedef __attribute__((ext_vector_type(2))) unsigned int uint2v;
typedef __attribute__((ext_vector_type(4))) unsigned int uint4v;

// Legacy CDNA spelling — no __has_builtin guard (false on host pass, R8 lesson)
#define MFMA16(a,b,c) __builtin_amdgcn_mfma_f32_16x16x16f16(a,b,c,0,0,0)

#if __has_builtin(__builtin_amdgcn_fdot2)
__device__ __forceinline__ float dot2u(unsigned a, unsigned b, float c) {
  return __builtin_amdgcn_fdot2(__builtin_bit_cast(f16x2, a),
                                __builtin_bit_cast(f16x2, b), c, false);
}
#else
__device__ __forceinline__ float dot2u(unsigned a, unsigned b, float c) {
  f16x2 ha = __builtin_bit_cast(f16x2, a), hb = __builtin_bit_cast(f16x2, b);
  return c + (float)ha[0] * (float)hb[0] + (float)ha[1] * (float)hb[1];
}
#endif

__device__ __forceinline__ f16x2 bch(unsigned u) { return __builtin_bit_cast(f16x2, u); }
__device__ __forceinline__ unsigned bcu(f16x2 h) { return __builtin_bit_cast(unsigned, h); }
__device__ __forceinline__ f16x4 fq(unsigned a, unsigned b) {
  uint2v u = {a, b};
  return __builtin_bit_cast(f16x4, u);
}

// XCD-aware bijective remap (grid % 8 == 0)
__device__ __forceinline__ int xcd_remap(int bid, int per) {
  return (bid & 7) * per + (bid >> 3);
}

// ---------------- Kernel T: NCHW fp32 -> NHWC f16 (verified R5 + swizzle) ---
__global__ __launch_bounds__(256) void transpose_kernel(
    const float* __restrict__ x, unsigned short* __restrict__ xt) {
  int t = threadIdx.x;
  int px = xcd_remap(blockIdx.x, NPIX / 64 / NXCD) * 64 + (t & 63);
  int cg = t >> 6;
  int b = px / HW, hw = px % HW;
  const float* xp = x + (size_t)b * CC * HW + (size_t)(cg * 16) * HW + hw;
  f16 r[16];
  #pragma unroll
  for (int i = 0; i < 16; ++i) r[i] = (f16)xp[i * HW];
  uint4v v0, v1;
  #pragma unroll
  for (int q = 0; q < 4; ++q) {
    f16x2 a = {r[q*2], r[q*2+1]};       v0[q] = bcu(a);
    f16x2 bq = {r[8+q*2], r[8+q*2+1]};  v1[q] = bcu(bq);
  }
  uint4v* dst = (uint4v*)(xt + (size_t)px * CC + cg * 16);
  dst[0] = v0; dst[1] = v1;
}

// ---------------- Kernel W: w_dcn [O][C][K2] fp32 -> wt [K2][O][C] f16 ------
__global__ void wprep_kernel(const float* __restrict__ w_dcn,
                             unsigned short* __restrict__ wt) {
  int idx = blockIdx.x * 256 + threadIdx.x;
  int k = idx / (OO * CC);
  int o = (idx / CC) % OO;
  int c = idx % CC;
  f16 h = (f16)w_dcn[(o * CC + c) * K2 + k];
  wt[idx] = __builtin_bit_cast(unsigned short, h);
}

// ---------------- Kernel O: offset conv via dot2 (verified R5 + swizzle) ----
#define JW 72
#define DOT4(xv, wv, a) do { a = dot2u((xv)[0],(wv)[0],a); a = dot2u((xv)[1],(wv)[1],a); \
                             a = dot2u((xv)[2],(wv)[2],a); a = dot2u((xv)[3],(wv)[3],a); } while(0)
#define DECLSET(R) uint4v R##0,R##1,R##2,R##3,R##4,R##5,R##6,R##7; bool vld##R = false;
#define LOADT(kt_, R) do { int ky=(kt_)/3, kx=(kt_)%3; int y=h-1+ky, xx=w-1+kx; \
  vld##R = ((unsigned)y<HH)&&((unsigned)xx<WW); \
  int yc=min(max(y,0),HH-1), xc=min(max(xx,0),WW-1); \
  const uint4v* xr_ = xtb + (size_t)(yc*WW+xc)*8; \
  R##0=xr_[0];R##1=xr_[1];R##2=xr_[2];R##3=xr_[3];R##4=xr_[4];R##5=xr_[5];R##6=xr_[6];R##7=xr_[7]; } while(0)
#define USET(kt_, R) do { if (vld##R) { \
  _Pragma("unroll") \
  for (int ji = 0; ji < 5; ++ji) { int j = jg + ji*4; \
    const uint4v* wr_ = (const uint4v*)&wl[((kt_)*NOFF + j)*JW]; \
    float a = acc[ji]; \
    DOT4(R##0,wr_[0],a); DOT4(R##1,wr_[1],a); DOT4(R##2,wr_[2],a); DOT4(R##3,wr_[3],a); \
    DOT4(R##4,wr_[4],a); DOT4(R##5,wr_[5],a); DOT4(R##6,wr_[6],a); DOT4(R##7,wr_[7],a); \
    if (j < NOFF) acc[ji] = a; } } } while(0)

__global__ __launch_bounds__(256) void offconv_kernel(
    const unsigned short* __restrict__ xt, const float* __restrict__ w_off,
    const float* __restrict__ b_off, float* __restrict__ offset) {
  __shared__ unsigned short wl[K2 * NOFF * JW + 2 * JW];
  int t = threadIdx.x;
  for (int i = t; i < K2 * NOFF * CC; i += 256) {
    int kt = i / (NOFF * CC);
    int r = i - kt * (NOFF * CC);
    int j = r >> 6, c = r & 63;
    f16 h = (f16)w_off[(j * CC + c) * K2 + kt];
    wl[(kt * NOFF + j) * JW + c] = __builtin_bit_cast(unsigned short, h);
  }
  __syncthreads();

  int px = xcd_remap(blockIdx.x, NPIX / 64 / NXCD) * 64 + (t >> 2);
  int jg = t & 3;
  int b = px / HW, hw = px % HW;
  int h = hw / WW, w = hw % WW;

  float acc[5];
  #pragma unroll
  for (int ji = 0; ji < 5; ++ji) {
    int j = jg + ji * 4;
    acc[ji] = (j < NOFF) ? b_off[j] : 0.f;
  }

  const uint4v* xtb = (const uint4v*)(xt + (size_t)b * HW * CC);
  DECLSET(A); DECLSET(B);
  LOADT(0, A);
  LOADT(1, B);
  #pragma unroll
  for (int kt = 0; kt < 7; kt += 2) {
    USET(kt, A);     LOADT(kt + 2, A);
    USET(kt + 1, B); if (kt + 3 < K2) LOADT(kt + 3, B);
  }
  USET(8, A);

  float* op = offset + (size_t)b * NOFF * HW + hw;
  #pragma unroll
  for (int ji = 0; ji < 5; ++ji) {
    int j = jg + ji * 4;
    if (j < NOFF) op[j * HW] = acc[ji];
  }
}

// ---------------- Kernel D: dcn MFMA — reg params, one branch, no barriers --
// R14 post-mortem: per-tap escape branch (if-conversion risk => dual gather
// paths) + prm-LDS round-trip + 6.6 waves/CU = latency collapse. This round:
//  * tile 2x32, window 6x36 (31 KB) staged once, read-only
//  * each lane loads its pixel's 18 offsets and computes ALL 9 taps' params
//    into static-indexed register arrays (+9-bit escape mask)
//  * ONE __ballot branch/wave: hot loop is branch-free LDS gather;
//    rare escape waves (~20 grid-wide) take the flagged fallback
//  * zero barriers after the single window barrier
// Blend/MFMA math bit-identical to R12/R14 (absmax 0.015625).
__global__ __launch_bounds__(256, 4) void dcn_mfma16(
    const unsigned short* __restrict__ xt,   // [B][HW][C] f16
    const float* __restrict__ offset,        // [B][18][HW] fp32
    const unsigned short* __restrict__ wt,   // [K2][O][C] f16
    float* __restrict__ out) {
  __shared__ char xwin[NWIN * WROWB];        // 31104 B

  int t = threadIdx.x;
  int blk = xcd_remap(blockIdx.x, NPIX / MT / NXCD);
  int b = blk / NTILE;
  int ti = blk % NTILE;
  int tr = ti / 3, tc = ti % 3;
  int h0 = tr * 2, w0 = tc * 32;             // tile rows h0..h0+1, cols w0..+31
  int hw0 = h0 * WW + w0;

  const char* xb = (const char*)(xt + (size_t)b * HW * CC);

  // ---- stage window: 216 rows x 128 B, coalesced, once ----
  for (int i = t; i < NWIN * 8; i += 256) {
    int row = i >> 3, seg = i & 7;
    int wr = row / WC, wc = row - wr * WC;
    int gy = min(max(h0 - 2 + wr, 0), HH - 1);
    int gx = min(max(w0 - 2 + wc, 0), WW - 1);
    *(uint4v*)&xwin[row * WROWB + (seg << 4)] =
        *(const uint4v*)(xb + (size_t)((gy * WW + gx) << 7) + (seg << 4));
  }

  // wave geometry (verified R9/R12)
  int wv = t >> 6;
  int l  = t & 63;
  int lr = l & 15, lh = l >> 4;
  int Ra = wv * 16 + lr;                     // this lane's pixel (0..63)
  int hpix = h0 + (Ra >> 5), wpix = w0 + (Ra & 31);
  int hwm = hpix * WW + wpix;
  int cB = lh * 32;                          // 32-B channel segment

  // ---- per-lane: 18 offsets, then all 9 taps' params in registers ----
  const float* offp = offset + (size_t)b * NOFF * HW + hwm;
  float offv[NOFF];
  #pragma unroll
  for (int j = 0; j < NOFF; ++j) offv[j] = offp[j * HW];

  unsigned po01[K2], po23[K2], pw01[K2], pw23[K2];
  unsigned emask = 0;
  #pragma unroll
  for (int k = 0; k < K2; ++k) {
    int ky = k / KK, kx = k % KK;
    float py = offv[2 * k]     + (float)(hpix - 1 + ky);
    float px = offv[2 * k + 1] + (float)(wpix - 1 + kx);
    float y0f = floorf(py), x0f = floorf(px);
    float wy = py - y0f, wx = px - x0f;
    int y0 = (int)y0f, x0 = (int)x0f;
    int y1 = y0 + 1, x1 = x0 + 1;
    bool vy0 = (unsigned)y0 < HH, vy1 = (unsigned)y1 < HH;
    bool vx0 = (unsigned)x0 < WW, vx1 = (unsigned)x1 < WW;
    int cy0 = min(max(y0, 0), HH - 1), cy1 = min(max(y1, 0), HH - 1);
    int cx0 = min(max(x0, 0), WW - 1), cx1 = min(max(x1, 0), WW - 1);
    float g00 = (1.f - wy) * (1.f - wx) * ((vy0 && vx0) ? 1.f : 0.f);
    float g01 = (1.f - wy) * wx         * ((vy0 && vx1) ? 1.f : 0.f);
    float g10 = wy * (1.f - wx)         * ((vy1 && vx0) ? 1.f : 0.f);
    float g11 = wy * wx                 * ((vy1 && vx1) ? 1.f : 0.f);
    int ry0 = cy0 - (h0 - 2), ry1 = cy1 - (h0 - 2);
    int rx0 = cx0 - (w0 - 2), rx1 = cx1 - (w0 - 2);
    bool inw = ((unsigned)ry0 < WR) && ((unsigned)ry1 < WR) &&
               ((unsigned)rx0 < WC) && ((unsigned)rx1 < WC);
    if (inw) {   // window byte offsets (<=30960, fits 15 bits)
      po01[k] = (unsigned)((ry0 * WC + rx0) * WROWB)
              | ((unsigned)((ry0 * WC + rx1) * WROWB) << 16);
      po23[k] = (unsigned)((ry1 * WC + rx0) * WROWB)
              | ((unsigned)((ry1 * WC + rx1) * WROWB) << 16);
    } else {     // image lin indices + flag bit 31 (rare)
      po01[k] = (unsigned)(cy0 * WW + cx0)
              | ((unsigned)(cy0 * WW + cx1) << 16) | 0x80000000u;
      po23[k] = (unsigned)(cy1 * WW + cx0)
              | ((unsigned)(cy1 * WW + cx1) << 16);
      emask |= 1u << k;
    }
    f16x2 wa = {(f16)g00, (f16)g01};
    f16x2 wb = {(f16)g10, (f16)g11};
    pw01[k] = bcu(wa);
    pw23[k] = bcu(wb);
  }
  __syncthreads();   // the ONLY block-wide barrier (window ready)

  f32x4 acc[4];
  #pragma unroll
  for (int nb = 0; nb < 4; ++nb) acc[nb] = (f32x4){0.f, 0.f, 0.f, 0.f};

  // blend + B-load + MFMA (bit-identical R12/R14 math)
  auto blend_mfma = [&](const char* wrow, unsigned w01, unsigned w23,
                        uint4v c0a, uint4v c0b, uint4v c1a, uint4v c1b,
                        uint4v c2a, uint4v c2b, uint4v c3a, uint4v c3b) {
    f16x2 wA = bch(w01), wB = bch(w23);
    f16x2 p0 = {wA[0], wA[0]}, p1 = {wA[1], wA[1]};
    f16x2 p2 = {wB[0], wB[0]}, p3 = {wB[1], wB[1]};
    uint4v pa, pb2;
    #pragma unroll
    for (int q = 0; q < 4; ++q) {
      f16x2 s  = p0 * bch(c0a[q]) + p1 * bch(c1a[q])
               + p2 * bch(c2a[q]) + p3 * bch(c3a[q]);
      pa[q] = bcu(s);
      f16x2 s2 = p0 * bch(c0b[q]) + p1 * bch(c1b[q])
               + p2 * bch(c2b[q]) + p3 * bch(c3b[q]);
      pb2[q] = bcu(s2);
    }
    f16x4 a0 = fq(pa[0],  pa[1]);
    f16x4 a1 = fq(pa[2],  pa[3]);
    f16x4 a2 = fq(pb2[0], pb2[1]);
    f16x4 a3 = fq(pb2[2], pb2[3]);
    #pragma unroll
    for (int nb = 0; nb < 4; ++nb) {
      const char* wp = wrow + (size_t)(nb * 16 + lr) * (CC * 2) + cB;
      uint4v u0 = *(const uint4v*)wp;
      uint4v u1 = *(const uint4v*)(wp + 16);
      f16x4 b0 = fq(u0[0], u0[1]);
      f16x4 b1 = fq(u0[2], u0[3]);
      f16x4 b2 = fq(u1[0], u1[1]);
      f16x4 b3 = fq(u1[2], u1[3]);
      acc[nb] = MFMA16(a0, b0, acc[nb]);
      acc[nb] = MFMA16(a1, b1, acc[nb]);
      acc[nb] = MFMA16(a2, b2, acc[nb]);
      acc[nb] = MFMA16(a3, b3, acc[nb]);
    }
  };

  if (__ballot(emask != 0) == 0ull) {
    // ---- hot path: branch-free window gathers, full cross-tap ILP ----
    #pragma unroll
    for (int k = 0; k < K2; ++k) {
      unsigned e0 = po01[k], e1 = po23[k];
      int i0 = (int)(e0 & 0xffffu), i1 = (int)(e0 >> 16);
      int i2 = (int)(e1 & 0xffffu), i3 = (int)(e1 >> 16);
      blend_mfma((const char*)wt + (size_t)k * OO * (CC * 2), pw01[k], pw23[k],
                 *(const uint4v*)&xwin[i0 + cB], *(const uint4v*)&xwin[i0 + cB + 16],
                 *(const uint4v*)&xwin[i1 + cB], *(const uint4v*)&xwin[i1 + cB + 16],
                 *(const uint4v*)&xwin[i2 + cB], *(const uint4v*)&xwin[i2 + cB + 16],
                 *(const uint4v*)&xwin[i3 + cB], *(const uint4v*)&xwin[i3 + cB + 16]);
    }
  } else {
    // ---- rare escape waves (~20 grid-wide): per-lane flagged gather ----
    #pragma unroll
    for (int k = 0; k < K2; ++k) {
      unsigned e0 = po01[k], e1 = po23[k];
      uint4v c0a, c0b, c1a, c1b, c2a, c2b, c3a, c3b;
      if ((int)e0 >= 0) {
        int i0 = (int)(e0 & 0xffffu), i1 = (int)(e0 >> 16);
        int i2 = (int)(e1 & 0xffffu), i3 = (int)(e1 >> 16);
        c0a = *(const uint4v*)&xwin[i0 + cB];
        c0b = *(const uint4v*)&xwin[i0 + cB + 16];
        c1a = *(const uint4v*)&xwin[i1 + cB];
        c1b = *(const uint4v*)&xwin[i1 + cB + 16];
        c2a = *(const uint4v*)&xwin[i2 + cB];
        c2b = *(const uint4v*)&xwin[i2 + cB + 16];
        c3a = *(const uint4v*)&xwin[i3 + cB];
        c3b = *(const uint4v*)&xwin[i3 + cB + 16];
      } else {
        int i0 = (int)(e0 & 0x7fffu) << 7;
        int i1 = (int)((e0 >> 16) & 0x7fffu) << 7;
        int i2 = (int)(e1 & 0x7fffu) << 7;
        int i3 = (int)((e1 >> 16) & 0x7fffu) << 7;
        c0a = *(const uint4v*)(xb + i0 + cB);
        c0b = *(const uint4v*)(xb + i0 + cB + 16);
        c1a = *(const uint4v*)(xb + i1 + cB);
        c1b = *(const uint4v*)(xb + i1 + cB + 16);
        c2a = *(const uint4v*)(xb + i2 + cB);
        c2b = *(const uint4v*)(xb + i2 + cB + 16);
        c3a = *(const uint4v*)(xb + i3 + cB);
        c3b = *(const uint4v*)(xb + i3 + cB + 16);
      }
      blend_mfma((const char*)wt + (size_t)k * OO * (CC * 2), pw01[k], pw23[k],
                 c0a, c0b, c1a, c1b, c2a, c2b, c3a, c3b);
    }
  }

  // ---- epilogue (verified R9/R12): pixel runs are 4-aligned, never cross
  // the 32-col tile-row boundary ----
  float* ob = out + (size_t)b * OO * HW;
  #pragma unroll
  for (int nb = 0; nb < 4; ++nb) {
    int o = nb * 16 + lr;
    int m = wv * 16 + lh * 4;
    int base = hw0 + (m >> 5) * WW + (m & 31);
    *(f32x4*)(ob + (size_t)o * HW + base) = acc[nb];
  }
}

extern "C" void kernel_launch(void* const* d_in, const int* in_sizes, int n_in,
                              void* d_out, int out_size, void* d_ws, size_t ws_size,
                              hipStream_t stream) {
  const float* x     = (const float*)d_in[0];
  const float* w_off = (const float*)d_in[1];
  const float* b_off = (const float*)d_in[2];
  const float* w_dcn = (const float*)d_in[3];
  float* out = (float*)d_out;

  char* ws = (char*)d_ws;
  float* offset = (float*)ws;                                      // 5,308,416 B
  unsigned short* xtp = (unsigned short*)(ws + 5308416);           // 9,437,184 B
  unsigned short* wtp = (unsigned short*)(ws + 5308416 + 9437184); //    73,728 B

  transpose_kernel<<<NPIX / 64, 256, 0, stream>>>(x, xtp);
  wprep_kernel<<<(K2 * OO * CC) / 256, 256, 0, stream>>>(w_dcn, wtp);
  offconv_kernel<<<NPIX / 64, 256, 0, stream>>>(xtp, w_off, b_off, offset);
  dcn_mfma16<<<NPIX / MT, 256, 0, stream>>>(xtp, offset, wtp, out);
}

// Round 16
// 93.708 us; speedup vs baseline: 1.3179x; 1.0060x over previous
//
#include <hip/hip_runtime.h>

#define BB 8
#define CC 64
#define HH 96
#define WW 96
#define OO 64
#define KK 3
#define K2 9
#define HW (HH*WW)      // 9216
#define NOFF 18
#define NPIX (BB*HW)    // 73728
#define MT 64           // pixels per dcn block: 2 rows x 32 cols
#define NTILE (HW/MT)   // 144 tiles per image (48 tile-rows x 3 tile-cols)
#define NXCD 8
// dcn LDS window: 6 rows x 36 cols of 128-B pixel rows, padded stride 144 B
#define WR 6
#define WC 36
#define WROWB 144
#define NWIN (WR*WC)    // 216

typedef _Float16 f16;
typedef __attribute__((ext_vector_type(2))) _Float16 f16x2;
typedef __attribute__((ext_vector_type(4))) _Float16 f16x4;
typedef __attribute__((ext_vector_type(4))) float f32x4;
typedef __attribute__((ext_vector_type(2))) unsigned int uint2v;
typedef __attribute__((ext_vector_type(4))) unsigned int uint4v;

// Legacy CDNA spelling — no __has_builtin guard (false on host pass, R8 lesson)
#define MFMA16(a,b,c) __builtin_amdgcn_mfma_f32_16x16x16f16(a,b,c,0,0,0)

#if __has_builtin(__builtin_amdgcn_fdot2)
__device__ __forceinline__ float dot2u(unsigned a, unsigned b, float c) {
  return __builtin_amdgcn_fdot2(__builtin_bit_cast(f16x2, a),
                                __builtin_bit_cast(f16x2, b), c, false);
}
#else
__device__ __forceinline__ float dot2u(unsigned a, unsigned b, float c) {
  f16x2 ha = __builtin_bit_cast(f16x2, a), hb = __builtin_bit_cast(f16x2, b);
  return c + (float)ha[0] * (float)hb[0] + (float)ha[1] * (float)hb[1];
}
#endif

__device__ __forceinline__ f16x2 bch(unsigned u) { return __builtin_bit_cast(f16x2, u); }
__device__ __forceinline__ unsigned bcu(f16x2 h) { return __builtin_bit_cast(unsigned, h); }
__device__ __forceinline__ f16x4 fq(unsigned a, unsigned b) {
  uint2v u = {a, b};
  return __builtin_bit_cast(f16x4, u);
}

// XCD-aware bijective remap (grid % 8 == 0)
__device__ __forceinline__ int xcd_remap(int bid, int per) {
  return (bid & 7) * per + (bid >> 3);
}

// ---------------- Kernel T: NCHW fp32 -> NHWC f16 (verified R5 + swizzle) ---
__global__ __launch_bounds__(256) void transpose_kernel(
    const float* __restrict__ x, unsigned short* __restrict__ xt) {
  int t = threadIdx.x;
  int px = xcd_remap(blockIdx.x, NPIX / 64 / NXCD) * 64 + (t & 63);
  int cg = t >> 6;
  int b = px / HW, hw = px % HW;
  const float* xp = x + (size_t)b * CC * HW + (size_t)(cg * 16) * HW + hw;
  f16 r[16];
  #pragma unroll
  for (int i = 0; i < 16; ++i) r[i] = (f16)xp[i * HW];
  uint4v v0, v1;
  #pragma unroll
  for (int q = 0; q < 4; ++q) {
    f16x2 a = {r[q*2], r[q*2+1]};       v0[q] = bcu(a);
    f16x2 bq = {r[8+q*2], r[8+q*2+1]};  v1[q] = bcu(bq);
  }
  uint4v* dst = (uint4v*)(xt + (size_t)px * CC + cg * 16);
  dst[0] = v0; dst[1] = v1;
}

// ---------------- Kernel W: w_dcn [O][C][K2] fp32 -> wt [K2][O][C] f16 ------
__global__ void wprep_kernel(const float* __restrict__ w_dcn,
                             unsigned short* __restrict__ wt) {
  int idx = blockIdx.x * 256 + threadIdx.x;
  int k = idx / (OO * CC);
  int o = (idx / CC) % OO;
  int c = idx % CC;
  f16 h = (f16)w_dcn[(o * CC + c) * K2 + k];
  wt[idx] = __builtin_bit_cast(unsigned short, h);
}

// ---------------- Kernel O: offset conv via dot2 (verified R5 + swizzle) ----
#define JW 72
#define DOT4(xv, wv, a) do { a = dot2u((xv)[0],(wv)[0],a); a = dot2u((xv)[1],(wv)[1],a); \
                             a = dot2u((xv)[2],(wv)[2],a); a = dot2u((xv)[3],(wv)[3],a); } while(0)
#define DECLSET(R) uint4v R##0,R##1,R##2,R##3,R##4,R##5,R##6,R##7; bool vld##R = false;
#define LOADT(kt_, R) do { int ky=(kt_)/3, kx=(kt_)%3; int y=h-1+ky, xx=w-1+kx; \
  vld##R = ((unsigned)y<HH)&&((unsigned)xx<WW); \
  int yc=min(max(y,0),HH-1), xc=min(max(xx,0),WW-1); \
  const uint4v* xr_ = xtb + (size_t)(yc*WW+xc)*8; \
  R##0=xr_[0];R##1=xr_[1];R##2=xr_[2];R##3=xr_[3];R##4=xr_[4];R##5=xr_[5];R##6=xr_[6];R##7=xr_[7]; } while(0)
#define USET(kt_, R) do { if (vld##R) { \
  _Pragma("unroll") \
  for (int ji = 0; ji < 5; ++ji) { int j = jg + ji*4; \
    const uint4v* wr_ = (const uint4v*)&wl[((kt_)*NOFF + j)*JW]; \
    float a = acc[ji]; \
    DOT4(R##0,wr_[0],a); DOT4(R##1,wr_[1],a); DOT4(R##2,wr_[2],a); DOT4(R##3,wr_[3],a); \
    DOT4(R##4,wr_[4],a); DOT4(R##5,wr_[5],a); DOT4(R##6,wr_[6],a); DOT4(R##7,wr_[7],a); \
    if (j < NOFF) acc[ji] = a; } } } while(0)

__global__ __launch_bounds__(256) void offconv_kernel(
    const unsigned short* __restrict__ xt, const float* __restrict__ w_off,
    const float* __restrict__ b_off, float* __restrict__ offset) {
  __shared__ unsigned short wl[K2 * NOFF * JW + 2 * JW];
  int t = threadIdx.x;
  for (int i = t; i < K2 * NOFF * CC; i += 256) {
    int kt = i / (NOFF * CC);
    int r = i - kt * (NOFF * CC);
    int j = r >> 6, c = r & 63;
    f16 h = (f16)w_off[(j * CC + c) * K2 + kt];
    wl[(kt * NOFF + j) * JW + c] = __builtin_bit_cast(unsigned short, h);
  }
  __syncthreads();

  int px = xcd_remap(blockIdx.x, NPIX / 64 / NXCD) * 64 + (t >> 2);
  int jg = t & 3;
  int b = px / HW, hw = px % HW;
  int h = hw / WW, w = hw % WW;

  float acc[5];
  #pragma unroll
  for (int ji = 0; ji < 5; ++ji) {
    int j = jg + ji * 4;
    acc[ji] = (j < NOFF) ? b_off[j] : 0.f;
  }

  const uint4v* xtb = (const uint4v*)(xt + (size_t)b * HW * CC);
  DECLSET(A); DECLSET(B);
  LOADT(0, A);
  LOADT(1, B);
  #pragma unroll
  for (int kt = 0; kt < 7; kt += 2) {
    USET(kt, A);     LOADT(kt + 2, A);
    USET(kt + 1, B); if (kt + 3 < K2) LOADT(kt + 3, B);
  }
  USET(8, A);

  float* op = offset + (size_t)b * NOFF * HW + hw;
  #pragma unroll
  for (int ji = 0; ji < 5; ++ji) {
    int j = jg + ji * 4;
    if (j < NOFF) op[j * HW] = acc[ji];
  }
}

// ---------------- Kernel D: dcn MFMA — 2-deep B-register pipeline -----------
// R15 post-mortem: VGPR squeezed to 64 in EVERY variant -> ~1 load in flight
// per wave -> ~170 serial load latencies = the whole 60 us. This round:
// launch_bounds(256,3) lifts the VGPR cap to ~170, and the hot loop keeps TWO
// named B-operand register sets (wbA/wbB, 64 VGPRs of in-flight data):
// tap k's MFMAs consume set X while set Y's 8 global loads fly. The 8 LDS
// corner reads batch-issue at the top of each tap. Math bit-identical
// R12/R14/R15 (absmax 0.015625).
#define BLOAD(S, k) do { \
  const char* wr_ = (const char*)wt + (size_t)(k) * OO * (CC * 2); \
  _Pragma("unroll") \
  for (int nb = 0; nb < 4; ++nb) { \
    const char* wp_ = wr_ + (size_t)(nb * 16 + lr) * (CC * 2) + cB; \
    wb##S[2*nb]   = *(const uint4v*)wp_; \
    wb##S[2*nb+1] = *(const uint4v*)(wp_ + 16); \
  } \
} while (0)

#define TAPH(X, Y, k, kn, PF) do { \
  unsigned e0 = po01[k], e1 = po23[k]; \
  int i0 = (int)(e0 & 0xffffu), i1 = (int)(e0 >> 16); \
  int i2 = (int)(e1 & 0xffffu), i3 = (int)(e1 >> 16); \
  uint4v c0a = *(const uint4v*)&xwin[i0 + cB]; \
  uint4v c0b = *(const uint4v*)&xwin[i0 + cB + 16]; \
  uint4v c1a = *(const uint4v*)&xwin[i1 + cB]; \
  uint4v c1b = *(const uint4v*)&xwin[i1 + cB + 16]; \
  uint4v c2a = *(const uint4v*)&xwin[i2 + cB]; \
  uint4v c2b = *(const uint4v*)&xwin[i2 + cB + 16]; \
  uint4v c3a = *(const uint4v*)&xwin[i3 + cB]; \
  uint4v c3b = *(const uint4v*)&xwin[i3 + cB + 16]; \
  if (PF) { BLOAD(Y, kn); } \
  f16x2 wA = bch(pw01[k]), wB = bch(pw23[k]); \
  f16x2 p0 = {wA[0], wA[0]}, p1 = {wA[1], wA[1]}; \
  f16x2 p2 = {wB[0], wB[0]}, p3 = {wB[1], wB[1]}; \
  uint4v pa, pb2; \
  _Pragma("unroll") \
  for (int q = 0; q < 4; ++q) { \
    f16x2 s  = p0 * bch(c0a[q]) + p1 * bch(c1a[q]) \
             + p2 * bch(c2a[q]) + p3 * bch(c3a[q]); \
    pa[q] = bcu(s); \
    f16x2 s2 = p0 * bch(c0b[q]) + p1 * bch(c1b[q]) \
             + p2 * bch(c2b[q]) + p3 * bch(c3b[q]); \
    pb2[q] = bcu(s2); \
  } \
  f16x4 a0 = fq(pa[0],  pa[1]); \
  f16x4 a1 = fq(pa[2],  pa[3]); \
  f16x4 a2 = fq(pb2[0], pb2[1]); \
  f16x4 a3 = fq(pb2[2], pb2[3]); \
  _Pragma("unroll") \
  for (int nb = 0; nb < 4; ++nb) { \
    f16x4 b0 = fq(wb##X[2*nb][0],   wb##X[2*nb][1]); \
    f16x4 b1 = fq(wb##X[2*nb][2],   wb##X[2*nb][3]); \
    f16x4 b2 = fq(wb##X[2*nb+1][0], wb##X[2*nb+1][1]); \
    f16x4 b3 = fq(wb##X[2*nb+1][2], wb##X[2*nb+1][3]); \
    acc[nb] = MFMA16(a0, b0, acc[nb]); \
    acc[nb] = MFMA16(a1, b1, acc[nb]); \
    acc[nb] = MFMA16(a2, b2, acc[nb]); \
    acc[nb] = MFMA16(a3, b3, acc[nb]); \
  } \
} while (0)

__global__ __launch_bounds__(256, 3) void dcn_mfma16(
    const unsigned short* __restrict__ xt,   // [B][HW][C] f16
    const float* __restrict__ offset,        // [B][18][HW] fp32
    const unsigned short* __restrict__ wt,   // [K2][O][C] f16
    float* __restrict__ out) {
  __shared__ char xwin[NWIN * WROWB];        // 31104 B

  int t = threadIdx.x;
  int blk = xcd_remap(blockIdx.x, NPIX / MT / NXCD);
  int b = blk / NTILE;
  int ti = blk % NTILE;
  int tr = ti / 3, tc = ti % 3;
  int h0 = tr * 2, w0 = tc * 32;             // tile rows h0..h0+1, cols w0..+31
  int hw0 = h0 * WW + w0;

  const char* xb = (const char*)(xt + (size_t)b * HW * CC);

  // ---- stage window: 216 rows x 128 B, coalesced, once ----
  for (int i = t; i < NWIN * 8; i += 256) {
    int row = i >> 3, seg = i & 7;
    int wr = row / WC, wc = row - wr * WC;
    int gy = min(max(h0 - 2 + wr, 0), HH - 1);
    int gx = min(max(w0 - 2 + wc, 0), WW - 1);
    *(uint4v*)&xwin[row * WROWB + (seg << 4)] =
        *(const uint4v*)(xb + (size_t)((gy * WW + gx) << 7) + (seg << 4));
  }

  // wave geometry (verified R9/R12)
  int wv = t >> 6;
  int l  = t & 63;
  int lr = l & 15, lh = l >> 4;
  int Ra = wv * 16 + lr;                     // this lane's pixel (0..63)
  int hpix = h0 + (Ra >> 5), wpix = w0 + (Ra & 31);
  int hwm = hpix * WW + wpix;
  int cB = lh * 32;                          // 32-B channel segment

  // ---- per-lane: 18 offsets, then all 9 taps' params in registers ----
  const float* offp = offset + (size_t)b * NOFF * HW + hwm;
  float offv[NOFF];
  #pragma unroll
  for (int j = 0; j < NOFF; ++j) offv[j] = offp[j * HW];

  unsigned po01[K2], po23[K2], pw01[K2], pw23[K2];
  unsigned emask = 0;
  #pragma unroll
  for (int k = 0; k < K2; ++k) {
    int ky = k / KK, kx = k % KK;
    float py = offv[2 * k]     + (float)(hpix - 1 + ky);
    float px = offv[2 * k + 1] + (float)(wpix - 1 + kx);
    float y0f = floorf(py), x0f = floorf(px);
    float wy = py - y0f, wx = px - x0f;
    int y0 = (int)y0f, x0 = (int)x0f;
    int y1 = y0 + 1, x1 = x0 + 1;
    bool vy0 = (unsigned)y0 < HH, vy1 = (unsigned)y1 < HH;
    bool vx0 = (unsigned)x0 < WW, vx1 = (unsigned)x1 < WW;
    int cy0 = min(max(y0, 0), HH - 1), cy1 = min(max(y1, 0), HH - 1);
    int cx0 = min(max(x0, 0), WW - 1), cx1 = min(max(x1, 0), WW - 1);
    float g00 = (1.f - wy) * (1.f - wx) * ((vy0 && vx0) ? 1.f : 0.f);
    float g01 = (1.f - wy) * wx         * ((vy0 && vx1) ? 1.f : 0.f);
    float g10 = wy * (1.f - wx)         * ((vy1 && vx0) ? 1.f : 0.f);
    float g11 = wy * wx                 * ((vy1 && vx1) ? 1.f : 0.f);
    int ry0 = cy0 - (h0 - 2), ry1 = cy1 - (h0 - 2);
    int rx0 = cx0 - (w0 - 2), rx1 = cx1 - (w0 - 2);
    bool inw = ((unsigned)ry0 < WR) && ((unsigned)ry1 < WR) &&
               ((unsigned)rx0 < WC) && ((unsigned)rx1 < WC);
    if (inw) {   // window byte offsets (<=30960, fits 15 bits)
      po01[k] = (unsigned)((ry0 * WC + rx0) * WROWB)
              | ((unsigned)((ry0 * WC + rx1) * WROWB) << 16);
      po23[k] = (unsigned)((ry1 * WC + rx0) * WROWB)
              | ((unsigned)((ry1 * WC + rx1) * WROWB) << 16);
    } else {     // image lin indices + flag bit 31 (rare)
      po01[k] = (unsigned)(cy0 * WW + cx0)
              | ((unsigned)(cy0 * WW + cx1) << 16) | 0x80000000u;
      po23[k] = (unsigned)(cy1 * WW + cx0)
              | ((unsigned)(cy1 * WW + cx1) << 16);
      emask |= 1u << k;
    }
    f16x2 wa = {(f16)g00, (f16)g01};
    f16x2 wb = {(f16)g10, (f16)g11};
    pw01[k] = bcu(wa);
    pw23[k] = bcu(wb);
  }
  __syncthreads();   // the ONLY block-wide barrier (window ready)

  f32x4 acc[4];
  #pragma unroll
  for (int nb = 0; nb < 4; ++nb) acc[nb] = (f32x4){0.f, 0.f, 0.f, 0.f};

  if (__ballot(emask != 0) == 0ull) {
    // ---- hot path: 2-deep B pipeline, batched LDS gathers, no barriers ----
    uint4v wbA[8], wbB[8];
    BLOAD(A, 0);
    TAPH(A, B, 0, 1, 1);
    TAPH(B, A, 1, 2, 1);
    TAPH(A, B, 2, 3, 1);
    TAPH(B, A, 3, 4, 1);
    TAPH(A, B, 4, 5, 1);
    TAPH(B, A, 5, 6, 1);
    TAPH(A, B, 6, 7, 1);
    TAPH(B, A, 7, 8, 1);
    TAPH(A, B, 8, 0, 0);
  } else {
    // ---- rare escape waves (~20 grid-wide): per-lane flagged gather ----
    #pragma unroll
    for (int k = 0; k < K2; ++k) {
      unsigned e0 = po01[k], e1 = po23[k];
      uint4v c0a, c0b, c1a, c1b, c2a, c2b, c3a, c3b;
      if ((int)e0 >= 0) {
        int i0 = (int)(e0 & 0xffffu), i1 = (int)(e0 >> 16);
        int i2 = (int)(e1 & 0xffffu), i3 = (int)(e1 >> 16);
        c0a = *(const uint4v*)&xwin[i0 + cB];
        c0b = *(const uint4v*)&xwin[i0 + cB + 16];
        c1a = *(const uint4v*)&xwin[i1 + cB];
        c1b = *(const uint4v*)&xwin[i1 + cB + 16];
        c2a = *(const uint4v*)&xwin[i2 + cB];
        c2b = *(const uint4v*)&xwin[i2 + cB + 16];
        c3a = *(const uint4v*)&xwin[i3 + cB];
        c3b = *(const uint4v*)&xwin[i3 + cB + 16];
      } else {
        int i0 = (int)(e0 & 0x7fffu) << 7;
        int i1 = (int)((e0 >> 16) & 0x7fffu) << 7;
        int i2 = (int)(e1 & 0x7fffu) << 7;
        int i3 = (int)((e1 >> 16) & 0x7fffu) << 7;
        c0a = *(const uint4v*)(xb + i0 + cB);
        c0b = *(const uint4v*)(xb + i0 + cB + 16);
        c1a = *(const uint4v*)(xb + i1 + cB);
        c1b = *(const uint4v*)(xb + i1 + cB + 16);
        c2a = *(const uint4v*)(xb + i2 + cB);
        c2b = *(const uint4v*)(xb + i2 + cB + 16);
        c3a = *(const uint4v*)(xb + i3 + cB);
        c3b = *(const uint4v*)(xb + i3 + cB + 16);
      }
      f16x2 wA = bch(pw01[k]), wB = bch(pw23[k]);
      f16x2 p0 = {wA[0], wA[0]}, p1 = {wA[1], wA[1]};
      f16x2 p2 = {wB[0], wB[0]}, p3 = {wB[1], wB[1]};
      uint4v pa, pb2;
      #pragma unroll
      for (int q = 0; q < 4; ++q) {
        f16x2 s  = p0 * bch(c0a[q]) + p1 * bch(c1a[q])
                 + p2 * bch(c2a[q]) + p3 * bch(c3a[q]);
        pa[q] = bcu(s);
        f16x2 s2 = p0 * bch(c0b[q]) + p1 * bch(c1b[q])
                 + p2 * bch(c2b[q]) + p3 * bch(c3b[q]);
        pb2[q] = bcu(s2);
      }
      f16x4 a0 = fq(pa[0],  pa[1]);
      f16x4 a1 = fq(pa[2],  pa[3]);
      f16x4 a2 = fq(pb2[0], pb2[1]);
      f16x4 a3 = fq(pb2[2], pb2[3]);
      const char* wrow = (const char*)wt + (size_t)k * OO * (CC * 2);
      #pragma unroll
      for (int nb = 0; nb < 4; ++nb) {
        const char* wp = wrow + (size_t)(nb * 16 + lr) * (CC * 2) + cB;
        uint4v u0 = *(const uint4v*)wp;
        uint4v u1 = *(const uint4v*)(wp + 16);
        f16x4 b0 = fq(u0[0], u0[1]);
        f16x4 b1 = fq(u0[2], u0[3]);
        f16x4 b2 = fq(u1[0], u1[1]);
        f16x4 b3 = fq(u1[2], u1[3]);
        acc[nb] = MFMA16(a0, b0, acc[nb]);
        acc[nb] = MFMA16(a1, b1, acc[nb]);
        acc[nb] = MFMA16(a2, b2, acc[nb]);
        acc[nb] = MFMA16(a3, b3, acc[nb]);
      }
    }
  }

  // ---- epilogue (verified R9/R12/R15) ----
  float* ob = out + (size_t)b * OO * HW;
  #pragma unroll
  for (int nb = 0; nb < 4; ++nb) {
    int o = nb * 16 + lr;
    int m = wv * 16 + lh * 4;
    int base = hw0 + (m >> 5) * WW + (m & 31);
    *(f32x4*)(ob + (size_t)o * HW + base) = acc[nb];
  }
}

extern "C" void kernel_launch(void* const* d_in, const int* in_sizes, int n_in,
                              void* d_out, int out_size, void* d_ws, size_t ws_size,
                              hipStream_t stream) {
  const float* x     = (const float*)d_in[0];
  const float* w_off = (const float*)d_in[1];
  const float* b_off = (const float*)d_in[2];
  const float* w_dcn = (const float*)d_in[3];
  float* out = (float*)d_out;

  char* ws = (char*)d_ws;
  float* offset = (float*)ws;                                      // 5,308,416 B
  unsigned short* xtp = (unsigned short*)(ws + 5308416);           // 9,437,184 B
  unsigned short* wtp = (unsigned short*)(ws + 5308416 + 9437184); //    73,728 B

  transpose_kernel<<<NPIX / 64, 256, 0, stream>>>(x, xtp);
  wprep_kernel<<<(K2 * OO * CC) / 256, 256, 0, stream>>>(w_dcn, wtp);
  offconv_kernel<<<NPIX / 64, 256, 0, stream>>>(xtp, w_off, b_off, offset);
  dcn_mfma16<<<NPIX / MT, 256, 0, stream>>>(xtp, offset, wtp, out);
}

// Round 17
// 89.177 us; speedup vs baseline: 1.3848x; 1.0508x over previous
//
#include <hip/hip_runtime.h>

#define BB 8
#define CC 64
#define HH 96
#define WW 96
#define OO 64
#define KK 3
#define K2 9
#define HW (HH*WW)      // 9216
#define NOFF 18
#define NPIX (BB*HW)    // 73728
#define MT 64           // pixels per fused block: 2 rows x 32 cols
#define NTILE (HW/MT)   // 144 tiles per image
#define NXCD 8
#define WR 6
#define WC 36
#define NWIN (WR*WC)    // 216 window pixel-rows, 128 B each (seg-swizzled)

typedef _Float16 f16;
typedef __attribute__((ext_vector_type(2))) _Float16 f16x2;
typedef __attribute__((ext_vector_type(4))) _Float16 f16x4;
typedef __attribute__((ext_vector_type(4))) float f32x4;
typedef __attribute__((ext_vector_type(2))) unsigned int uint2v;
typedef __attribute__((ext_vector_type(4))) unsigned int uint4v;

#define MFMA16(a,b,c) __builtin_amdgcn_mfma_f32_16x16x16f16(a,b,c,0,0,0)

#if __has_builtin(__builtin_amdgcn_fdot2)
__device__ __forceinline__ float dot2u(unsigned a, unsigned b, float c) {
  return __builtin_amdgcn_fdot2(__builtin_bit_cast(f16x2, a),
                                __builtin_bit_cast(f16x2, b), c, false);
}
#else
__device__ __forceinline__ float dot2u(unsigned a, unsigned b, float c) {
  f16x2 ha = __builtin_bit_cast(f16x2, a), hb = __builtin_bit_cast(f16x2, b);
  return c + (float)ha[0] * (float)hb[0] + (float)ha[1] * (float)hb[1];
}
#endif

__device__ __forceinline__ f16x2 bch(unsigned u) { return __builtin_bit_cast(f16x2, u); }
__device__ __forceinline__ unsigned bcu(f16x2 h) { return __builtin_bit_cast(unsigned, h); }
__device__ __forceinline__ f16x4 fq(unsigned a, unsigned b) {
  uint2v u = {a, b};
  return __builtin_bit_cast(f16x4, u);
}
__device__ __forceinline__ int xcd_remap(int bid, int per) {
  return (bid & 7) * per + (bid >> 3);
}

// ---------------- Kernel T: NCHW fp32 -> NHWC f16 (verified R5) -------------
__global__ __launch_bounds__(256) void transpose_kernel(
    const float* __restrict__ x, unsigned short* __restrict__ xt) {
  int t = threadIdx.x;
  int px = xcd_remap(blockIdx.x, NPIX / 64 / NXCD) * 64 + (t & 63);
  int cg = t >> 6;
  int b = px / HW, hw = px % HW;
  const float* xp = x + (size_t)b * CC * HW + (size_t)(cg * 16) * HW + hw;
  f16 r[16];
  #pragma unroll
  for (int i = 0; i < 16; ++i) r[i] = (f16)xp[i * HW];
  uint4v v0, v1;
  #pragma unroll
  for (int q = 0; q < 4; ++q) {
    f16x2 a = {r[q*2], r[q*2+1]};       v0[q] = bcu(a);
    f16x2 bq = {r[8+q*2], r[8+q*2+1]};  v1[q] = bcu(bq);
  }
  uint4v* dst = (uint4v*)(xt + (size_t)px * CC + cg * 16);
  dst[0] = v0; dst[1] = v1;
}

// ---------------- Kernel W: w_dcn -> wt [K2][O][C] f16 (verified) -----------
__global__ void wprep_kernel(const float* __restrict__ w_dcn,
                             unsigned short* __restrict__ wt) {
  int idx = blockIdx.x * 256 + threadIdx.x;
  int k = idx / (OO * CC);
  int o = (idx / CC) % OO;
  int c = idx % CC;
  f16 h = (f16)w_dcn[(o * CC + c) * K2 + k];
  wt[idx] = __builtin_bit_cast(unsigned short, h);
}

// ---------------- Kernel W2: w_off [18][64][9] fp32 -> wof [9][18][64] f16 --
__global__ void woffprep_kernel(const float* __restrict__ w_off,
                                unsigned short* __restrict__ wof) {
  int idx = blockIdx.x * 256 + threadIdx.x;   // 9*18*64 = 10368
  if (idx >= K2 * NOFF * CC) return;
  int kt = idx / (NOFF * CC);
  int j = (idx / CC) % NOFF;
  int c = idx % CC;
  f16 h = (f16)w_off[(j * CC + c) * K2 + kt];
  wof[idx] = __builtin_bit_cast(unsigned short, h);
}

// ---------------- Kernel F: fused offconv + dcn -----------------------------
// 512 threads / 8 waves, 64-pixel tile (2x32), window 6x36 staged once.
// P1: in-block offset conv (R5-verified dot2, A from window, W from LDS).
// P2: params in registers (R15-verified math), taps K-split across groups.
// P3: dcn MFMA taps: group0 = taps 0-4, group1 = taps 5-8 (R15-verified).
// P4: f32 acc-reduce via LDS (reassoc ~1e-6), group0 stores.
// All LDS rows seg-swizzled: content seg s lives at position s^(row&7)
// (kills the 128-B-stride same-bank alias, G4).
#define XWIN_OFF 0
#define WL_OFF   27648
#define OFFS_OFF 48384
#define ACCX_OFF WL_OFF   // accx aliases wl (dead after P1)
#define SMEM_SZ  52992

__global__ __launch_bounds__(512, 4) void fused_kernel(
    const unsigned short* __restrict__ xt,   // [B][HW][C] f16
    const unsigned short* __restrict__ wof,  // [K2][18][C] f16
    const float* __restrict__ b_off,         // [18] fp32
    const unsigned short* __restrict__ wt,   // [K2][O][C] f16
    float* __restrict__ out) {
  __shared__ __align__(16) char smem[SMEM_SZ];
  char* xwin = smem + XWIN_OFF;      // 216 x 128 B, seg-swizzled
  char* wl   = smem + WL_OFF;        // 162 x 128 B, seg-swizzled
  float* offs = (float*)(smem + OFFS_OFF);   // [64][18]
  float* accx = (float*)(smem + ACCX_OFF);   // [64 o][68 px] padded

  int t = threadIdx.x;
  int blk = xcd_remap(blockIdx.x, NPIX / MT / NXCD);
  int b = blk / NTILE;
  int ti = blk % NTILE;
  int tr = ti / 3, tc = ti % 3;
  int h0 = tr * 2, w0 = tc * 32;
  int hw0 = h0 * WW + w0;

  const char* xb = (const char*)(xt + (size_t)b * HW * CC);

  // ---- P0: stage window + w_off tile, seg-swizzled ----
  #pragma unroll
  for (int r = 0; r < 4; ++r) {
    int d = r * 512 + t;                     // 16-B chunk id, 1728 total
    if (d < NWIN * 8) {
      int row = d >> 3, sg = d & 7;
      int wr_ = row / WC, wc_ = row - wr_ * WC;
      int gy = min(max(h0 - 2 + wr_, 0), HH - 1);
      int gx = min(max(w0 - 2 + wc_, 0), WW - 1);
      uint4v v = *(const uint4v*)(xb + (size_t)((gy * WW + gx) << 7) + (sg << 4));
      *(uint4v*)&xwin[row * 128 + ((sg ^ (row & 7)) << 4)] = v;
    }
  }
  #pragma unroll
  for (int r = 0; r < 3; ++r) {
    int d = r * 512 + t;                     // 1296 total
    if (d < K2 * NOFF * 8) {
      int row = d >> 3, sg = d & 7;
      uint4v v = *(const uint4v*)((const char*)wof + (size_t)d * 16);
      *(uint4v*)&wl[row * 128 + ((sg ^ (row & 7)) << 4)] = v;
    }
  }
  __syncthreads();

  // ---- P1: offset conv (dot2, R5 accumulation order) ----
  {
    int px = t >> 3, jg = t & 7;
    int hpix = h0 + (px >> 5), wpix = w0 + (px & 31);
    float ao[3];
    #pragma unroll
    for (int ji = 0; ji < 3; ++ji) {
      int j = jg + ji * 8;
      ao[ji] = (j < NOFF) ? b_off[j] : 0.f;
    }
    for (int kt = 0; kt < K2; ++kt) {
      int ky = kt / 3, kx = kt % 3;
      int y = hpix - 1 + ky, xx = wpix - 1 + kx;
      if (((unsigned)y < HH) && ((unsigned)xx < WW)) {
        int row = (y - (h0 - 2)) * WC + (xx - (w0 - 2));
        int rs = row & 7;
        uint4v xr[8];
        #pragma unroll
        for (int s = 0; s < 8; ++s)
          xr[s] = *(const uint4v*)&xwin[row * 128 + ((s ^ rs) << 4)];
        #pragma unroll
        for (int ji = 0; ji < 3; ++ji) {
          int j = jg + ji * 8;
          if (j < NOFF) {
            int row2 = kt * NOFF + j;
            int rs2 = row2 & 7;
            float a = ao[ji];
            #pragma unroll
            for (int s = 0; s < 8; ++s) {
              uint4v wv_ = *(const uint4v*)&wl[row2 * 128 + ((s ^ rs2) << 4)];
              a = dot2u(xr[s][0], wv_[0], a);
              a = dot2u(xr[s][1], wv_[1], a);
              a = dot2u(xr[s][2], wv_[2], a);
              a = dot2u(xr[s][3], wv_[3], a);
            }
            ao[ji] = a;
          }
        }
      }
    }
    #pragma unroll
    for (int ji = 0; ji < 3; ++ji) {
      int j = jg + ji * 8;
      if (j < NOFF) offs[px * NOFF + j] = ao[ji];
    }
  }
  __syncthreads();

  // ---- P2: per-lane params for this group's taps (R15 math) ----
  int wv = t >> 6;
  int l  = t & 63;
  int lr = l & 15, lh = l >> 4;
  int grp = wv >> 2;
  int base = grp * 5;                  // g0: taps 0..4, g1: taps 5..8
  int cnt  = 5 - grp;
  int Ra = (wv & 3) * 16 + lr;
  int hpix = h0 + (Ra >> 5), wpix = w0 + (Ra & 31);
  int cB = lh * 32;

  unsigned po01[5], po23[5], pw01[5], pw23[5];
  unsigned emask = 0;
  #pragma unroll
  for (int i = 0; i < 5; ++i) {
    po01[i] = 0; po23[i] = 0; pw01[i] = 0; pw23[i] = 0;
    if (i < cnt) {
      int kt = base + i;
      int ky = kt / 3, kx = kt % 3;
      float py = offs[Ra * NOFF + 2 * kt]     + (float)(hpix - 1 + ky);
      float px = offs[Ra * NOFF + 2 * kt + 1] + (float)(wpix - 1 + kx);
      float y0f = floorf(py), x0f = floorf(px);
      float wy = py - y0f, wx = px - x0f;
      int y0 = (int)y0f, x0 = (int)x0f;
      int y1 = y0 + 1, x1 = x0 + 1;
      bool vy0 = (unsigned)y0 < HH, vy1 = (unsigned)y1 < HH;
      bool vx0 = (unsigned)x0 < WW, vx1 = (unsigned)x1 < WW;
      int cy0 = min(max(y0, 0), HH - 1), cy1 = min(max(y1, 0), HH - 1);
      int cx0 = min(max(x0, 0), WW - 1), cx1 = min(max(x1, 0), WW - 1);
      float g00 = (1.f - wy) * (1.f - wx) * ((vy0 && vx0) ? 1.f : 0.f);
      float g01 = (1.f - wy) * wx         * ((vy0 && vx1) ? 1.f : 0.f);
      float g10 = wy * (1.f - wx)         * ((vy1 && vx0) ? 1.f : 0.f);
      float g11 = wy * wx                 * ((vy1 && vx1) ? 1.f : 0.f);
      int ry0 = cy0 - (h0 - 2), ry1 = cy1 - (h0 - 2);
      int rx0 = cx0 - (w0 - 2), rx1 = cx1 - (w0 - 2);
      bool inw = ((unsigned)ry0 < WR) && ((unsigned)ry1 < WR) &&
                 ((unsigned)rx0 < WC) && ((unsigned)rx1 < WC);
      if (inw) {   // window byte bases (<27648, fits 15 bits)
        po01[i] = (unsigned)((ry0 * WC + rx0) << 7)
                | ((unsigned)((ry0 * WC + rx1) << 7) << 16);
        po23[i] = (unsigned)((ry1 * WC + rx0) << 7)
                | ((unsigned)((ry1 * WC + rx1) << 7) << 16);
      } else {
        po01[i] = (unsigned)(cy0 * WW + cx0)
                | ((unsigned)(cy0 * WW + cx1) << 16) | 0x80000000u;
        po23[i] = (unsigned)(cy1 * WW + cx0)
                | ((unsigned)(cy1 * WW + cx1) << 16);
        emask |= 1u << i;
      }
      f16x2 wa = {(f16)g00, (f16)g01};
      f16x2 wb = {(f16)g10, (f16)g11};
      pw01[i] = bcu(wa);
      pw23[i] = bcu(wb);
    }
  }

  f32x4 acc[4];
  #pragma unroll
  for (int nb = 0; nb < 4; ++nb) acc[nb] = (f32x4){0.f, 0.f, 0.f, 0.f};

  // ---- P3: dcn taps (R15-verified blend/MFMA; window reads swizzled) ----
  #define WREAD(bo, pos) (*(const uint4v*)&xwin[(bo) + ((pos) << 4)])
  if (__ballot(emask != 0) == 0ull) {
    #pragma unroll
    for (int i = 0; i < 5; ++i) {
      if (i < cnt) {
        unsigned e0 = po01[i], e1 = po23[i];
        int i0 = (int)(e0 & 0xffffu), i1 = (int)(e0 >> 16);
        int i2 = (int)(e1 & 0xffffu), i3 = (int)(e1 >> 16);
        int s0 = lh * 2;
        int p00 = s0 ^ ((i0 >> 7) & 7), p01 = (s0 + 1) ^ ((i0 >> 7) & 7);
        int p10 = s0 ^ ((i1 >> 7) & 7), p11 = (s0 + 1) ^ ((i1 >> 7) & 7);
        int p20 = s0 ^ ((i2 >> 7) & 7), p21 = (s0 + 1) ^ ((i2 >> 7) & 7);
        int p30 = s0 ^ ((i3 >> 7) & 7), p31 = (s0 + 1) ^ ((i3 >> 7) & 7);
        uint4v c0a = WREAD(i0, p00), c0b = WREAD(i0, p01);
        uint4v c1a = WREAD(i1, p10), c1b = WREAD(i1, p11);
        uint4v c2a = WREAD(i2, p20), c2b = WREAD(i2, p21);
        uint4v c3a = WREAD(i3, p30), c3b = WREAD(i3, p31);
        f16x2 wA = bch(pw01[i]), wB = bch(pw23[i]);
        f16x2 p0 = {wA[0], wA[0]}, p1 = {wA[1], wA[1]};
        f16x2 p2 = {wB[0], wB[0]}, p3 = {wB[1], wB[1]};
        uint4v pa, pb2;
        #pragma unroll
        for (int q = 0; q < 4; ++q) {
          f16x2 s  = p0 * bch(c0a[q]) + p1 * bch(c1a[q])
                   + p2 * bch(c2a[q]) + p3 * bch(c3a[q]);
          pa[q] = bcu(s);
          f16x2 s2 = p0 * bch(c0b[q]) + p1 * bch(c1b[q])
                   + p2 * bch(c2b[q]) + p3 * bch(c3b[q]);
          pb2[q] = bcu(s2);
        }
        f16x4 a0 = fq(pa[0],  pa[1]);
        f16x4 a1 = fq(pa[2],  pa[3]);
        f16x4 a2 = fq(pb2[0], pb2[1]);
        f16x4 a3 = fq(pb2[2], pb2[3]);
        const char* wrow = (const char*)wt + (size_t)(base + i) * OO * (CC * 2);
        #pragma unroll
        for (int nb = 0; nb < 4; ++nb) {
          const char* wp = wrow + (size_t)(nb * 16 + lr) * (CC * 2) + cB;
          uint4v u0 = *(const uint4v*)wp;
          uint4v u1 = *(const uint4v*)(wp + 16);
          acc[nb] = MFMA16(a0, fq(u0[0], u0[1]), acc[nb]);
          acc[nb] = MFMA16(a1, fq(u0[2], u0[3]), acc[nb]);
          acc[nb] = MFMA16(a2, fq(u1[0], u1[1]), acc[nb]);
          acc[nb] = MFMA16(a3, fq(u1[2], u1[3]), acc[nb]);
        }
      }
    }
  } else {
    #pragma unroll
    for (int i = 0; i < 5; ++i) {
      if (i < cnt) {
        unsigned e0 = po01[i], e1 = po23[i];
        uint4v c0a, c0b, c1a, c1b, c2a, c2b, c3a, c3b;
        if ((int)e0 >= 0) {
          int i0 = (int)(e0 & 0xffffu), i1 = (int)(e0 >> 16);
          int i2 = (int)(e1 & 0xffffu), i3 = (int)(e1 >> 16);
          int s0 = lh * 2;
          c0a = WREAD(i0, s0 ^ ((i0 >> 7) & 7));
          c0b = WREAD(i0, (s0 + 1) ^ ((i0 >> 7) & 7));
          c1a = WREAD(i1, s0 ^ ((i1 >> 7) & 7));
          c1b = WREAD(i1, (s0 + 1) ^ ((i1 >> 7) & 7));
          c2a = WREAD(i2, s0 ^ ((i2 >> 7) & 7));
          c2b = WREAD(i2, (s0 + 1) ^ ((i2 >> 7) & 7));
          c3a = WREAD(i3, s0 ^ ((i3 >> 7) & 7));
          c3b = WREAD(i3, (s0 + 1) ^ ((i3 >> 7) & 7));
        } else {
          int i0 = (int)(e0 & 0x7fffu) << 7;
          int i1 = (int)((e0 >> 16) & 0x7fffu) << 7;
          int i2 = (int)(e1 & 0x7fffu) << 7;
          int i3 = (int)((e1 >> 16) & 0x7fffu) << 7;
          c0a = *(const uint4v*)(xb + i0 + cB);
          c0b = *(const uint4v*)(xb + i0 + cB + 16);
          c1a = *(const uint4v*)(xb + i1 + cB);
          c1b = *(const uint4v*)(xb + i1 + cB + 16);
          c2a = *(const uint4v*)(xb + i2 + cB);
          c2b = *(const uint4v*)(xb + i2 + cB + 16);
          c3a = *(const uint4v*)(xb + i3 + cB);
          c3b = *(const uint4v*)(xb + i3 + cB + 16);
        }
        f16x2 wA = bch(pw01[i]), wB = bch(pw23[i]);
        f16x2 p0 = {wA[0], wA[0]}, p1 = {wA[1], wA[1]};
        f16x2 p2 = {wB[0], wB[0]}, p3 = {wB[1], wB[1]};
        uint4v pa, pb2;
        #pragma unroll
        for (int q = 0; q < 4; ++q) {
          f16x2 s  = p0 * bch(c0a[q]) + p1 * bch(c1a[q])
                   + p2 * bch(c2a[q]) + p3 * bch(c3a[q]);
          pa[q] = bcu(s);
          f16x2 s2 = p0 * bch(c0b[q]) + p1 * bch(c1b[q])
                   + p2 * bch(c2b[q]) + p3 * bch(c3b[q]);
          pb2[q] = bcu(s2);
        }
        f16x4 a0 = fq(pa[0],  pa[1]);
        f16x4 a1 = fq(pa[2],  pa[3]);
        f16x4 a2 = fq(pb2[0], pb2[1]);
        f16x4 a3 = fq(pb2[2], pb2[3]);
        const char* wrow = (const char*)wt + (size_t)(base + i) * OO * (CC * 2);
        #pragma unroll
        for (int nb = 0; nb < 4; ++nb) {
          const char* wp = wrow + (size_t)(nb * 16 + lr) * (CC * 2) + cB;
          uint4v u0 = *(const uint4v*)wp;
          uint4v u1 = *(const uint4v*)(wp + 16);
          acc[nb] = MFMA16(a0, fq(u0[0], u0[1]), acc[nb]);
          acc[nb] = MFMA16(a1, fq(u0[2], u0[3]), acc[nb]);
          acc[nb] = MFMA16(a2, fq(u1[0], u1[1]), acc[nb]);
          acc[nb] = MFMA16(a3, fq(u1[2], u1[3]), acc[nb]);
        }
      }
    }
  }
  __syncthreads();   // window dead; accx (alias wl) exchange

  // ---- P4: group1 -> accx, group0 adds + stores (accx [o][68 px] padded) ----
  if (grp == 1) {
    #pragma unroll
    for (int nb = 0; nb < 4; ++nb)
      *(f32x4*)&accx[(nb * 16 + lr) * 68 + (wv & 3) * 16 + lh * 4] = acc[nb];
  }
  __syncthreads();
  if (grp == 0) {
    float* ob = out + (size_t)b * OO * HW;
    #pragma unroll
    for (int nb = 0; nb < 4; ++nb) {
      f32x4 other = *(const f32x4*)&accx[(nb * 16 + lr) * 68 + (wv & 3) * 16 + lh * 4];
      f32x4 v = acc[nb] + other;
      int o = nb * 16 + lr;
      int m = (wv & 3) * 16 + lh * 4;
      int base2 = hw0 + (m >> 5) * WW + (m & 31);
      *(f32x4*)(ob + (size_t)o * HW + base2) = v;
    }
  }
}

extern "C" void kernel_launch(void* const* d_in, const int* in_sizes, int n_in,
                              void* d_out, int out_size, void* d_ws, size_t ws_size,
                              hipStream_t stream) {
  const float* x     = (const float*)d_in[0];
  const float* w_off = (const float*)d_in[1];
  const float* b_off = (const float*)d_in[2];
  const float* w_dcn = (const float*)d_in[3];
  float* out = (float*)d_out;

  char* ws = (char*)d_ws;
  unsigned short* xtp = (unsigned short*)ws;                  // 9,437,184 B
  unsigned short* wtp = (unsigned short*)(ws + 9437184);      //    73,728 B
  unsigned short* wof = (unsigned short*)(ws + 9437184 + 73728); // 20,736 B

  transpose_kernel<<<NPIX / 64, 256, 0, stream>>>(x, xtp);
  wprep_kernel<<<(K2 * OO * CC) / 256, 256, 0, stream>>>(w_dcn, wtp);
  woffprep_kernel<<<(K2 * NOFF * CC + 255) / 256, 256, 0, stream>>>(w_off, wof);
  fused_kernel<<<NPIX / MT, 512, 0, stream>>>(xtp, wof, b_off, wtp, out);
}